// Round 7
// baseline (747.542 us; speedup 1.0000x reference)
//
#include <hip/hip_runtime.h>

typedef _Float16 f16;
typedef _Float16 f16x8 __attribute__((ext_vector_type(8)));
typedef _Float16 h2 __attribute__((ext_vector_type(2)));
typedef float f32x4 __attribute__((ext_vector_type(4)));
typedef unsigned short u16;
typedef unsigned int u32;

// ---------- conversions ----------
__device__ __forceinline__ float bf2f(u16 b) {
  union { u32 u; float f; } t; t.u = ((u32)b) << 16; return t.f;
}
__device__ __forceinline__ u16 f2bf(float f) {  // RNE float->bf16 bits
  union { float f; u32 u; } t; t.f = f;
  u32 u = t.u;
  return (u16)((u + 0x7FFFu + ((u >> 16) & 1u)) >> 16);
}
__device__ __forceinline__ u16 f2h_bits(float f) {
  f16 h = (f16)f;
  union { f16 h; u16 u; } t; t.h = h; return t.u;
}
__device__ __forceinline__ float2 up2(u32 p) {  // f16 pair -> float2
  union { u32 u; f16 h[2]; } t; t.u = p;
  float2 r; r.x = (float)t.h[0]; r.y = (float)t.h[1]; return r;
}
__device__ __forceinline__ u32 pk2(float x, float y) {  // float2 -> f16 pair
  return (u32)f2h_bits(x) | ((u32)f2h_bits(y) << 16);
}
__device__ __forceinline__ h2 asH2(u32 u) {
  union { u32 u; h2 h; } t; t.u = u; return t.h;
}
__device__ __forceinline__ h2 relu2(h2 a) {
#if __has_builtin(__builtin_elementwise_max)
  h2 z = {(_Float16)0, (_Float16)0};
  return __builtin_elementwise_max(a, z);
#else
  h2 r;
  r.x = a.x > (_Float16)0 ? a.x : (_Float16)0;
  r.y = a.y > (_Float16)0 ? a.y : (_Float16)0;
  return r;
#endif
}

// ---------------- dtype detection ----------------
__global__ void k_detect(const u16* __restrict__ elemRaw, const int* __restrict__ eiRaw,
                         int* __restrict__ dflags) {
  __shared__ int bad, nzOdd;
  if (threadIdx.x == 0) { bad = 0; nzOdd = 0; }
  __syncthreads();
  int myBad = 0;
  for (int i = threadIdx.x; i < 4096; i += 256) {
    float v = bf2f(elemRaw[i]);
    if (!(v > -0.2f && v < 0.2f)) myBad++;
  }
  if (myBad) atomicAdd(&bad, myBad);
  int myNz = 0;
  for (int i = threadIdx.x; i < 1024; i += 256)
    if (eiRaw[2 * i + 1] != 0) myNz++;  // int64 high words would be 0
  if (myNz) atomicAdd(&nzOdd, myNz);
  __syncthreads();
  if (threadIdx.x == 0) {
    dflags[0] = (bad == 0) ? 1 : 0;
    dflags[1] = (nzOdd > 16) ? 1 : 0;
  }
}

__global__ void k_canary(u32* __restrict__ out, const int* __restrict__ dflags,
                         int out_size, u32 pBf, u32 pF32) {
  int isbf = dflags[0];
  int words = isbf ? (out_size >> 1) : out_size;
  int i = blockIdx.x * 256 + threadIdx.x;
  if (i < words) out[i] = isbf ? pBf : pF32;
}

// ---------------- zero ----------------
__global__ void k_zero(int* counts, float* stats, int NPad) {
  int i = blockIdx.x * blockDim.x + threadIdx.x;
  if (i < NPad) counts[i] = 0;
  else if (i < NPad + 1280) stats[i - NPad] = 0.f;
}

// ---------------- combined canonicalize (+fused dst histogram) ----------------
__global__ void k_cvt(const int* __restrict__ xR, const int* __restrict__ eiR,
                      const int* __restrict__ eaR,
                      const u16* e0, const u16* e1, const u16* e2, const u16* e3,
                      const u16* e4, const u16* e5, const u16* e6, const u16* e7,
                      const u16* e8, const u16* e9,
                      const int* __restrict__ dflags,
                      int* __restrict__ x32, int* __restrict__ ei32, int* __restrict__ combo,
                      int* __restrict__ counts, float* __restrict__ dst,
                      int N, int E, int intBlocks) {
  if ((int)blockIdx.x < intBlocks) {
    int pi = blockIdx.x * 256 + threadIdx.x;
    int nPairs = N + 2 * E;
    if (pi >= nPairs) return;
    int is32 = dflags[1];
    const int* src; int local; int kind;
    if (pi < N) { src = xR; local = pi; kind = 0; }
    else if (pi < N + E) { src = eiR; local = pi - N; kind = 1; }
    else { src = eaR; local = pi - N - E; kind = 2; }
    int j0 = 2 * local;
    int v0, v1;
    if (is32) { int2 v = *(const int2*)(src + j0); v0 = v.x; v1 = v.y; }
    else      { int4 v = *(const int4*)(src + 2 * j0); v0 = v.x; v1 = v.z; }
    if (kind == 0) { x32[j0] = v0; x32[j0 + 1] = v1; }
    else if (kind == 1) {
      ei32[j0] = v0; ei32[j0 + 1] = v1;
      if (j0 >= E) {  // dst half
        atomicAdd(&counts[v0], 1);
        atomicAdd(&counts[v1], 1);
      }
    } else {
      combo[local] = v0 * 3 + v1;
    }
  } else {
    int i = (blockIdx.x - intBlocks) * 256 + threadIdx.x;
    if (i >= 83712) return;
    int isbf = dflags[0];
    const u16* src; int j;
    if      (i < 15104) { src = e0; j = i; }
    else if (i < 15616) { src = e1; j = i - 15104; }
    else if (i < 16128) { src = e2; j = i - 15616; }
    else if (i < 16512) { src = e3; j = i - 16128; }
    else if (i < 49280) { src = e4; j = i - 16512; }
    else if (i < 49536) { src = e5; j = i - 49280; }
    else if (i < 82304) { src = e6; j = i - 49536; }
    else if (i < 82432) { src = e7; j = i - 82304; }
    else if (i < 83072) { src = e8; j = i - 82432; }
    else                { src = e9; j = i - 83072; }
    dst[i] = isbf ? bf2f(src[j]) : ((const float*)src)[j];
  }
}

// ---------------- CSR scan ----------------
__global__ void k_chunksum(const int* __restrict__ counts, int* __restrict__ bsum) {
  int tid = threadIdx.x, lane = tid & 63, w = tid >> 6;
  const int4* c4 = (const int4*)(counts + blockIdx.x * 1024);
  int4 v = c4[tid];
  int s = v.x + v.y + v.z + v.w;
#pragma unroll
  for (int d = 1; d < 64; d <<= 1) s += __shfl_xor(s, d);
  __shared__ int ws[4];
  if (lane == 0) ws[w] = s;
  __syncthreads();
  if (tid == 0) bsum[blockIdx.x] = ws[0] + ws[1] + ws[2] + ws[3];
}

__global__ void k_chunkscan(const int* __restrict__ bsum, int* __restrict__ boff,
                            int* __restrict__ row_start, int N, int nCh) {
  int t = threadIdx.x;
  int v = (t < nCh) ? bsum[t] : 0;
  int incl = v;
#pragma unroll
  for (int d = 1; d < 64; d <<= 1) { int tmp = __shfl_up(incl, d); if (t >= d) incl += tmp; }
  boff[t] = incl - v;
  if (t == 63) row_start[N] = incl;  // = E
}

__global__ void k_scanapply(const int* __restrict__ counts, const int* __restrict__ boff,
                            int* __restrict__ row_start, int* __restrict__ cursor, int N) {
  int tid = threadIdx.x, lane = tid & 63, w = tid >> 6;
  int base = blockIdx.x * 1024 + tid * 4;
  int4 v = *(const int4*)(counts + base);
  int tsum = v.x + v.y + v.z + v.w;
  int incl = tsum;
#pragma unroll
  for (int d = 1; d < 64; d <<= 1) { int tmp = __shfl_up(incl, d); if (lane >= d) incl += tmp; }
  __shared__ int ws[4];
  if (lane == 63) ws[w] = incl;
  __syncthreads();
  int woff = 0;
  for (int j = 0; j < w; ++j) woff += ws[j];
  int excl = boff[blockIdx.x] + woff + incl - tsum;
  int e0 = excl, e1 = excl + v.x, e2 = e1 + v.y, e3 = e2 + v.z;
  if (base < N)     { row_start[base] = e0;     cursor[base] = e0; }
  if (base + 1 < N) { row_start[base + 1] = e1; cursor[base + 1] = e1; }
  if (base + 2 < N) { row_start[base + 2] = e2; cursor[base + 2] = e2; }
  if (base + 3 < N) { row_start[base + 3] = e3; cursor[base + 3] = e3; }
}

__global__ void k_scatter(const int* __restrict__ ei, const int* __restrict__ combo,
                          int* cursor, int* packed, int E) {
  int e = blockIdx.x * blockDim.x + threadIdx.x;
  if (e >= E) return;
  int s = ei[e], d = ei[E + e];
  int cb = combo[e];
  int pos = atomicAdd(&cursor[d], 1);
  packed[pos] = s | (cb << 20);  // src < 2^20, combo in [0,12)
}

// ---------------- weights transpose + bond table + h0 (merged) ----------------
__global__ void k_prep(const float* __restrict__ cflt, const int* __restrict__ x,
                       u16* W1T, u16* W2T, u32* __restrict__ tblC,
                       u32* __restrict__ hb, int N, int wtBlocks) {
  if ((int)blockIdx.x < wtBlocks) {
    const float* W1 = cflt + 16512;
    const float* W2 = cflt + 49536;
    const float* bt = cflt + 15616;
    const float* bd = cflt + 16128;
    int g = blockIdx.x * 256 + threadIdx.x;  // 0..32767
    int k1 = g >> 8, n1 = g & 255;
    W1T[n1 * 128 + k1] = f2h_bits(W1[g]);   // [256 n][128 k]
    int k2 = g >> 7, n2 = g & 127;
    W2T[n2 * 256 + k2] = f2h_bits(W2[g]);   // [128 n][256 k]
    if (g < 768) {
      int combo = g >> 6, l = g & 63, c0 = l * 2;
      int a0 = combo / 3, a1 = combo - a0 * 3;
      tblC[g] = pk2(bt[a0 * 128 + c0] + bd[a1 * 128 + c0],
                    bt[a0 * 128 + c0 + 1] + bd[a1 * 128 + c0 + 1]);
    }
  } else {
    const float* elem = cflt;
    const float* chir = cflt + 15104;
    int b = blockIdx.x - wtBlocks;
    int wv = (int)(threadIdx.x >> 6);
    int lane = threadIdx.x & 63;
    int node = b * 4 + wv;
    if (node >= N) return;
    int x0 = x[node * 2], x1 = x[node * 2 + 1];
    int c0 = lane * 2;
    float vx = elem[x0 * 128 + c0] + chir[x1 * 128 + c0];
    float vy = elem[x0 * 128 + c0 + 1] + chir[x1 * 128 + c0 + 1];
    hb[(size_t)node * 64 + lane] = pk2(vx, vy);
  }
}

// ---------------- gather/aggregate (pure; BN pre-applied in hb) ----------------
__global__ __launch_bounds__(256) void k_agg(
    const u32* __restrict__ hb, const int* __restrict__ row_start,
    const int* __restrict__ packed, const u32* __restrict__ tblC,
    u32* __restrict__ z, int N, int Mpad) {
  __shared__ u32 tbl[768];
  for (int idx = threadIdx.x; idx < 768; idx += 256) tbl[idx] = tblC[idx];
  __syncthreads();
  int wv = __builtin_amdgcn_readfirstlane((int)(threadIdx.x >> 6));
  int lane = threadIdx.x & 63;
  int node = blockIdx.x * 4 + wv;
  if (node >= Mpad) return;
  if (node >= N) { z[(size_t)node * 64 + lane] = 0u; return; }
  float2 sv = up2(hb[(size_t)node * 64 + lane]);
  float accx = sv.x, accy = sv.y;  // z = h + sum(msg)
  int s_ = row_start[node], e_ = row_start[node + 1];
  int p = s_;
  for (; p + 4 <= e_; p += 4) {
    int k0 = packed[p], k1 = packed[p + 1], k2 = packed[p + 2], k3 = packed[p + 3];
    u32 r0 = hb[(size_t)(k0 & 0xFFFFF) * 64 + lane];
    u32 r1 = hb[(size_t)(k1 & 0xFFFFF) * 64 + lane];
    u32 r2 = hb[(size_t)(k2 & 0xFFFFF) * 64 + lane];
    u32 r3 = hb[(size_t)(k3 & 0xFFFFF) * 64 + lane];
    u32 t0 = tbl[(k0 >> 20) * 64 + lane];
    u32 t1 = tbl[(k1 >> 20) * 64 + lane];
    u32 t2 = tbl[(k2 >> 20) * 64 + lane];
    u32 t3 = tbl[(k3 >> 20) * 64 + lane];
    h2 m0 = relu2(asH2(r0) + asH2(t0));
    h2 m1 = relu2(asH2(r1) + asH2(t1));
    h2 m2 = relu2(asH2(r2) + asH2(t2));
    h2 m3 = relu2(asH2(r3) + asH2(t3));
    accx += (float)m0.x + (float)m1.x + (float)m2.x + (float)m3.x;
    accy += (float)m0.y + (float)m1.y + (float)m2.y + (float)m3.y;
  }
  for (; p < e_; ++p) {
    int k0 = packed[p];
    u32 r0 = hb[(size_t)(k0 & 0xFFFFF) * 64 + lane];
    u32 t0 = tbl[(k0 >> 20) * 64 + lane];
    h2 m0 = relu2(asH2(r0) + asH2(t0));
    accx += (float)m0.x;
    accy += (float)m0.y;
  }
  z[(size_t)node * 64 + lane] = pk2(accx, accy);
}

// ---------------- barrier-free fused MLP + BN-stat partials ----------------
// One wave owns 16 rows end-to-end. W fragments: global->register (L1/L2-hot).
// Y transform through wave-PRIVATE LDS slice -> only lgkmcnt ordering, no barriers.
__global__ __launch_bounds__(256) void k_mlp(
    const u16* __restrict__ z, const u16* __restrict__ W1T, const u16* __restrict__ W2T,
    const float* __restrict__ b1, const float* __restrict__ b2,
    u16* __restrict__ act, float* __restrict__ statsL, int N) {
  __shared__ u16 sZ[64 * 128];       // 16KB shared Z tile (swizzled)
  __shared__ u16 sYp[4][16 * 64];    // 8KB: per-wave private Y slice
  __shared__ float sRed[4][2][128];  // 4KB

  const int tid = threadIdx.x;
  const int w = tid >> 6, lane = tid & 63;
  const int lo = lane & 15, q = lane >> 4;
  const int row0 = blockIdx.x * 64;

  // stage Z tile (coalesced 16B, XOR-swizzled)
#pragma unroll
  for (int t = 0; t < 4; ++t) {
    int L = t * 4096 + tid * 16;
    int row = L >> 8, slot = (L >> 4) & 15;
    int kb = slot ^ (row & 15);
    *(int4*)((char*)sZ + L) =
        *(const int4*)((const char*)z + (size_t)(row0 + row) * 256 + kb * 16);
  }
  __syncthreads();  // the only data barrier

  // A1-fragments for this wave's 16 rows (full K=128)
  const int rw = w * 16 + lo;
  f16x8 a1[4];
#pragma unroll
  for (int ks = 0; ks < 4; ++ks) {
    int kq = ks * 4 + q;
    a1[ks] = *(const f16x8*)(sZ + rw * 128 + ((kq ^ lo) << 3));
  }

  u16* myY = sYp[w];
  f32x4 accO[8] = {};
#pragma unroll
  for (int c = 0; c < 4; ++c) {
    // GEMM1: Y[16 x 64] = Z[16 x 128] @ W1[:, c*64 : c*64+64)
    f32x4 acc1[4] = {};
#pragma unroll
    for (int ks = 0; ks < 4; ++ks) {
      int kq = ks * 4 + q;
      f16x8 b[4];
#pragma unroll
      for (int nt = 0; nt < 4; ++nt) {
        int n = c * 64 + nt * 16 + lo;
        b[nt] = *(const f16x8*)((const char*)W1T + (size_t)n * 256 + kq * 16);
      }
#pragma unroll
      for (int nt = 0; nt < 4; ++nt)
        acc1[nt] = __builtin_amdgcn_mfma_f32_16x16x32_f16(a1[ks], b[nt], acc1[nt], 0, 0, 0);
    }
    // bias + relu -> private Y (C-layout scatter, swizzled)
#pragma unroll
    for (int nt = 0; nt < 4; ++nt) {
      int ycol = nt * 16 + lo;
      float bias = b1[c * 64 + ycol];
#pragma unroll
      for (int i = 0; i < 4; ++i) {
        int m = q * 4 + i;
        float v = fmaxf(acc1[nt][i] + bias, 0.f);
        myY[m * 64 + (((ycol >> 3) ^ (m & 7)) << 3) + (ycol & 7)] = f2h_bits(v);
      }
    }
    // GEMM2 partial: OUT += Y @ W2[c*64 : c*64+64, :]  (same-wave LDS dep only)
#pragma unroll
    for (int ks2 = 0; ks2 < 2; ++ks2) {
      int kq2 = ks2 * 4 + q;
      f16x8 a2 = *(const f16x8*)(myY + lo * 64 + ((kq2 ^ (lo & 7)) << 3));
      f16x8 bb[8];
#pragma unroll
      for (int nt = 0; nt < 8; ++nt) {
        int n2 = nt * 16 + lo;
        bb[nt] = *(const f16x8*)((const char*)W2T + (size_t)n2 * 512 + c * 128 + kq2 * 16);
      }
#pragma unroll
      for (int nt = 0; nt < 8; ++nt)
        accO[nt] = __builtin_amdgcn_mfma_f32_16x16x32_f16(a2, bb[nt], accO[nt], 0, 0, 0);
    }
  }

  // epilogue: +b2, f16 store, BN-stat partials
#pragma unroll
  for (int nt = 0; nt < 8; ++nt) {
    int n2 = nt * 16 + lo;
    float bias = b2[n2];
    float ssum = 0.f, ssq = 0.f;
#pragma unroll
    for (int i = 0; i < 4; ++i) {
      int row = row0 + w * 16 + q * 4 + i;
      float v = accO[nt][i] + bias;
      act[(size_t)row * 128 + n2] = f2h_bits(v);
      if (row < N) { ssum += v; ssq += v * v; }
    }
    ssum += __shfl_xor(ssum, 16); ssum += __shfl_xor(ssum, 32);
    ssq  += __shfl_xor(ssq, 16);  ssq  += __shfl_xor(ssq, 32);
    if (q == 0) { sRed[w][0][n2] = ssum; sRed[w][1][n2] = ssq; }
  }
  __syncthreads();
  {
    int col = tid & 127, which = (tid >> 7) & 1;
    float s = sRed[0][which][col] + sRed[1][which][col] +
              sRed[2][which][col] + sRed[3][which][col];
    atomicAdd(&statsL[which * 128 + col], s);
  }
}

// ---------------- BN apply + relu (per node, computes sc/sh in-block) ----------------
__global__ __launch_bounds__(256) void k_bnapply(
    const u32* __restrict__ act, const float* __restrict__ statsL,
    const float* __restrict__ gamma, const float* __restrict__ beta,
    float invN, u32* __restrict__ hb, int N) {
  __shared__ float ssc[128], ssh[128];
  int tid = threadIdx.x;
  if (tid < 128) {
    float mean = statsL[tid] * invN;
    float var = statsL[128 + tid] * invN - mean * mean;
    float inv = rsqrtf(var + 1e-5f);
    float scv = gamma[tid] * inv;
    ssc[tid] = scv;
    ssh[tid] = beta[tid] - mean * scv;
  }
  __syncthreads();
  int total = N * 64;
  for (int i = blockIdx.x * 256 + tid; i < total; i += gridDim.x * 256) {
    int c0 = (i & 63) * 2;
    float2 v = up2(act[i]);
    float ox = fmaxf(v.x * ssc[c0] + ssh[c0], 0.f);
    float oy = fmaxf(v.y * ssc[c0 + 1] + ssh[c0 + 1], 0.f);
    hb[i] = pk2(ox, oy);
  }
}

// ---------------- final: BN (no relu) -> output dtype ----------------
__global__ __launch_bounds__(256) void k_final(
    const u32* __restrict__ act, const float* __restrict__ statsL,
    const float* __restrict__ gamma, const float* __restrict__ beta,
    float invN, const int* __restrict__ dflags, void* __restrict__ outv, int N) {
  __shared__ float ssc[128], ssh[128];
  int tid = threadIdx.x;
  if (tid < 128) {
    float mean = statsL[tid] * invN;
    float var = statsL[128 + tid] * invN - mean * mean;
    float inv = rsqrtf(var + 1e-5f);
    float scv = gamma[tid] * inv;
    ssc[tid] = scv;
    ssh[tid] = beta[tid] - mean * scv;
  }
  __syncthreads();
  int isbf = dflags[0];
  int total = N * 64;
  for (int i = blockIdx.x * 256 + tid; i < total; i += gridDim.x * 256) {
    int c0 = (i & 63) * 2;
    float2 v = up2(act[i]);
    float ox = v.x * ssc[c0] + ssh[c0];
    float oy = v.y * ssc[c0 + 1] + ssh[c0 + 1];
    if (isbf) ((u32*)outv)[i] = (u32)f2bf(ox) | ((u32)f2bf(oy) << 16);
    else { float2 o; o.x = ox; o.y = oy; ((float2*)outv)[i] = o; }
  }
}

extern "C" void kernel_launch(void* const* d_in, const int* in_sizes, int n_in,
                              void* d_out, int out_size, void* d_ws, size_t ws_size,
                              hipStream_t stream) {
  const int* xR  = (const int*)d_in[0];
  const int* eiR = (const int*)d_in[1];
  const int* eaR = (const int*)d_in[2];
  const u16* emR = (const u16*)d_in[3];
  const u16* chR = (const u16*)d_in[4];
  const u16* btR = (const u16*)d_in[5];
  const u16* bdR = (const u16*)d_in[6];
  const u16* W1R = (const u16*)d_in[7];
  const u16* b1R = (const u16*)d_in[8];
  const u16* W2R = (const u16*)d_in[9];
  const u16* b2R = (const u16*)d_in[10];
  const u16* gR  = (const u16*)d_in[11];
  const u16* beR = (const u16*)d_in[12];

  const int N = in_sizes[0] / 2;      // 50000
  const int E = in_sizes[1] / 2;      // 600000
  const int L = in_sizes[11] / 128;   // 5
  const int Mpad = ((N + 63) / 64) * 64;
  const int nCh = (N + 1023) / 1024;
  const int NPad = nCh * 1024;

  char* base = (char*)d_ws;
  size_t off = 0;
  auto take = [&](size_t bytes) -> void* {
    void* p = base + off;
    off += (bytes + 255) & ~(size_t)255;
    return p;
  };
  int*   dflags    = (int*)  take(256);
  int*   x32       = (int*)  take((size_t)2 * N * 4);
  int*   ei32      = (int*)  take((size_t)2 * E * 4);
  int*   combo     = (int*)  take((size_t)E * 4);
  float* cflt      = (float*)take(83712 * 4);
  u32*   act       = (u32*)  take((size_t)Mpad * 64 * 4);   // raw MLP out (f16 pairs)
  u32*   hb        = (u32*)  take((size_t)Mpad * 64 * 4);   // BN-applied relu'd h
  u16*   zb        = (u16*)  take((size_t)Mpad * 128 * 2);
  int*   packed    = (int*)  take((size_t)E * 4);
  int*   row_start = (int*)  take((size_t)(N + 1) * 4);
  int*   cursor    = (int*)  take((size_t)N * 4);
  int*   counts    = (int*)  take((size_t)NPad * 4);
  int*   bsum      = (int*)  take(64 * 4);
  int*   boff      = (int*)  take(64 * 4);
  float* stats     = (float*)take((size_t)L * 256 * 4);
  u16*   W1T       = (u16*)  take(32768 * 2);
  u16*   W2T       = (u16*)  take(32768 * 2);
  u32*   tblC      = (u32*)  take(768 * 4);
  const size_t need = off;
  (void)n_in;

  float* cB1 = cflt + 49280;
  float* cB2 = cflt + 82304;
  float* cGamma = cflt + 82432;
  float* cBeta = cflt + 83072;

  k_detect<<<dim3(1), dim3(256), 0, stream>>>(emR, eiR, dflags);

  if (need > ws_size) {
    k_canary<<<dim3((out_size + 255) / 256), dim3(256), 0, stream>>>(
        (u32*)d_out, dflags, out_size, 0x40004000u, 0x40000000u);
    return;
  }

  k_zero<<<dim3((NPad + 1280 + 255) / 256), dim3(256), 0, stream>>>(counts, stats, NPad);

  const int nPairs = N + 2 * E;
  const int intBlocks = (nPairs + 255) / 256;
  const int fltBlocks = (83712 + 255) / 256;
  k_cvt<<<dim3(intBlocks + fltBlocks), dim3(256), 0, stream>>>(
      xR, eiR, eaR, emR, chR, btR, bdR, W1R, b1R, W2R, b2R, gR, beR,
      dflags, x32, ei32, combo, counts, cflt, N, E, intBlocks);

  k_chunksum<<<dim3(nCh), dim3(256), 0, stream>>>(counts, bsum);
  k_chunkscan<<<dim3(1), dim3(64), 0, stream>>>(bsum, boff, row_start, N, nCh);
  k_scanapply<<<dim3(nCh), dim3(256), 0, stream>>>(counts, boff, row_start, cursor, N);
  k_scatter<<<dim3((E + 255) / 256), dim3(256), 0, stream>>>(ei32, combo, cursor, packed, E);

  const int wtBlocks = 128;
  k_prep<<<dim3(wtBlocks + (N + 3) / 4), dim3(256), 0, stream>>>(
      cflt, x32, W1T, W2T, tblC, hb, N, wtBlocks);

  const float invN = 1.0f / (float)N;
  for (int l = 0; l < L; ++l) {
    k_agg<<<dim3(Mpad / 4), dim3(256), 0, stream>>>(
        hb, row_start, packed, tblC, (u32*)zb, N, Mpad);
    k_mlp<<<dim3(Mpad / 64), dim3(256), 0, stream>>>(
        zb, W1T, W2T, cB1, cB2, (u16*)act, stats + (size_t)l * 256, N);
    if (l < L - 1) {
      k_bnapply<<<dim3(1024), dim3(256), 0, stream>>>(
          act, stats + (size_t)l * 256, cGamma + (size_t)l * 128, cBeta + (size_t)l * 128,
          invN, hb, N);
    }
  }
  k_final<<<dim3(1024), dim3(256), 0, stream>>>(
      act, stats + (size_t)(L - 1) * 256, cGamma + (size_t)(L - 1) * 128,
      cBeta + (size_t)(L - 1) * 128, invN, dflags, d_out, N);
}

// Round 8
// 649.800 us; speedup vs baseline: 1.1504x; 1.1504x over previous
//
#include <hip/hip_runtime.h>

typedef _Float16 f16;
typedef _Float16 f16x8 __attribute__((ext_vector_type(8)));
typedef _Float16 h2 __attribute__((ext_vector_type(2)));
typedef float f32x4 __attribute__((ext_vector_type(4)));
typedef unsigned short u16;
typedef unsigned int u32;

// ---------- conversions ----------
__device__ __forceinline__ float bf2f(u16 b) {
  union { u32 u; float f; } t; t.u = ((u32)b) << 16; return t.f;
}
__device__ __forceinline__ u16 f2bf(float f) {  // RNE float->bf16 bits
  union { float f; u32 u; } t; t.f = f;
  u32 u = t.u;
  return (u16)((u + 0x7FFFu + ((u >> 16) & 1u)) >> 16);
}
__device__ __forceinline__ u16 f2h_bits(float f) {
  f16 h = (f16)f;
  union { f16 h; u16 u; } t; t.h = h; return t.u;
}
__device__ __forceinline__ float2 up2(u32 p) {  // f16 pair -> float2
  union { u32 u; f16 h[2]; } t; t.u = p;
  float2 r; r.x = (float)t.h[0]; r.y = (float)t.h[1]; return r;
}
__device__ __forceinline__ u32 pk2(float x, float y) {  // float2 -> f16 pair
  return (u32)f2h_bits(x) | ((u32)f2h_bits(y) << 16);
}
__device__ __forceinline__ h2 asH2(u32 u) {
  union { u32 u; h2 h; } t; t.u = u; return t.h;
}
__device__ __forceinline__ h2 relu2(h2 a) {
#if __has_builtin(__builtin_elementwise_max)
  h2 z = {(_Float16)0, (_Float16)0};
  return __builtin_elementwise_max(a, z);
#else
  h2 r;
  r.x = a.x > (_Float16)0 ? a.x : (_Float16)0;
  r.y = a.y > (_Float16)0 ? a.y : (_Float16)0;
  return r;
#endif
}

// ---------------- dtype detection ----------------
__global__ void k_detect(const u16* __restrict__ elemRaw, const int* __restrict__ eiRaw,
                         int* __restrict__ dflags) {
  __shared__ int bad, nzOdd;
  if (threadIdx.x == 0) { bad = 0; nzOdd = 0; }
  __syncthreads();
  int myBad = 0;
  for (int i = threadIdx.x; i < 4096; i += 256) {
    float v = bf2f(elemRaw[i]);
    if (!(v > -0.2f && v < 0.2f)) myBad++;
  }
  if (myBad) atomicAdd(&bad, myBad);
  int myNz = 0;
  for (int i = threadIdx.x; i < 1024; i += 256)
    if (eiRaw[2 * i + 1] != 0) myNz++;  // int64 high words would be 0
  if (myNz) atomicAdd(&nzOdd, myNz);
  __syncthreads();
  if (threadIdx.x == 0) {
    dflags[0] = (bad == 0) ? 1 : 0;
    dflags[1] = (nzOdd > 16) ? 1 : 0;
  }
}

__global__ void k_canary(u32* __restrict__ out, const int* __restrict__ dflags,
                         int out_size, u32 pBf, u32 pF32) {
  int isbf = dflags[0];
  int words = isbf ? (out_size >> 1) : out_size;
  int i = blockIdx.x * 256 + threadIdx.x;
  if (i < words) out[i] = isbf ? pBf : pF32;
}

// ---------------- zero ----------------
__global__ void k_zero(int* counts, float* stats, int NPad) {
  int i = blockIdx.x * blockDim.x + threadIdx.x;
  if (i < NPad) counts[i] = 0;
  else if (i < NPad + 1280) stats[i - NPad] = 0.f;
}

// ---------------- combined canonicalize (+fused dst histogram) ----------------
__global__ void k_cvt(const int* __restrict__ xR, const int* __restrict__ eiR,
                      const int* __restrict__ eaR,
                      const u16* e0, const u16* e1, const u16* e2, const u16* e3,
                      const u16* e4, const u16* e5, const u16* e6, const u16* e7,
                      const u16* e8, const u16* e9,
                      const int* __restrict__ dflags,
                      int* __restrict__ x32, int* __restrict__ ei32, int* __restrict__ combo,
                      int* __restrict__ counts, float* __restrict__ dst,
                      int N, int E, int intBlocks) {
  if ((int)blockIdx.x < intBlocks) {
    int pi = blockIdx.x * 256 + threadIdx.x;
    int nPairs = N + 2 * E;
    if (pi >= nPairs) return;
    int is32 = dflags[1];
    const int* src; int local; int kind;
    if (pi < N) { src = xR; local = pi; kind = 0; }
    else if (pi < N + E) { src = eiR; local = pi - N; kind = 1; }
    else { src = eaR; local = pi - N - E; kind = 2; }
    int j0 = 2 * local;
    int v0, v1;
    if (is32) { int2 v = *(const int2*)(src + j0); v0 = v.x; v1 = v.y; }
    else      { int4 v = *(const int4*)(src + 2 * j0); v0 = v.x; v1 = v.z; }
    if (kind == 0) { x32[j0] = v0; x32[j0 + 1] = v1; }
    else if (kind == 1) {
      ei32[j0] = v0; ei32[j0 + 1] = v1;
      if (j0 >= E) {  // dst half
        atomicAdd(&counts[v0], 1);
        atomicAdd(&counts[v1], 1);
      }
    } else {
      combo[local] = v0 * 3 + v1;
    }
  } else {
    int i = (blockIdx.x - intBlocks) * 256 + threadIdx.x;
    if (i >= 83712) return;
    int isbf = dflags[0];
    const u16* src; int j;
    if      (i < 15104) { src = e0; j = i; }
    else if (i < 15616) { src = e1; j = i - 15104; }
    else if (i < 16128) { src = e2; j = i - 15616; }
    else if (i < 16512) { src = e3; j = i - 16128; }
    else if (i < 49280) { src = e4; j = i - 16512; }
    else if (i < 49536) { src = e5; j = i - 49280; }
    else if (i < 82304) { src = e6; j = i - 49536; }
    else if (i < 82432) { src = e7; j = i - 82304; }
    else if (i < 83072) { src = e8; j = i - 82432; }
    else                { src = e9; j = i - 83072; }
    dst[i] = isbf ? bf2f(src[j]) : ((const float*)src)[j];
  }
}

// ---------------- CSR scan ----------------
__global__ void k_chunksum(const int* __restrict__ counts, int* __restrict__ bsum) {
  int tid = threadIdx.x, lane = tid & 63, w = tid >> 6;
  const int4* c4 = (const int4*)(counts + blockIdx.x * 1024);
  int4 v = c4[tid];
  int s = v.x + v.y + v.z + v.w;
#pragma unroll
  for (int d = 1; d < 64; d <<= 1) s += __shfl_xor(s, d);
  __shared__ int ws[4];
  if (lane == 0) ws[w] = s;
  __syncthreads();
  if (tid == 0) bsum[blockIdx.x] = ws[0] + ws[1] + ws[2] + ws[3];
}

__global__ void k_chunkscan(const int* __restrict__ bsum, int* __restrict__ boff,
                            int* __restrict__ row_start, int N, int nCh) {
  int t = threadIdx.x;
  int v = (t < nCh) ? bsum[t] : 0;
  int incl = v;
#pragma unroll
  for (int d = 1; d < 64; d <<= 1) { int tmp = __shfl_up(incl, d); if (t >= d) incl += tmp; }
  boff[t] = incl - v;
  if (t == 63) row_start[N] = incl;  // = E
}

__global__ void k_scanapply(const int* __restrict__ counts, const int* __restrict__ boff,
                            int* __restrict__ row_start, int* __restrict__ cursor, int N) {
  int tid = threadIdx.x, lane = tid & 63, w = tid >> 6;
  int base = blockIdx.x * 1024 + tid * 4;
  int4 v = *(const int4*)(counts + base);
  int tsum = v.x + v.y + v.z + v.w;
  int incl = tsum;
#pragma unroll
  for (int d = 1; d < 64; d <<= 1) { int tmp = __shfl_up(incl, d); if (lane >= d) incl += tmp; }
  __shared__ int ws[4];
  if (lane == 63) ws[w] = incl;
  __syncthreads();
  int woff = 0;
  for (int j = 0; j < w; ++j) woff += ws[j];
  int excl = boff[blockIdx.x] + woff + incl - tsum;
  int e0 = excl, e1 = excl + v.x, e2 = e1 + v.y, e3 = e2 + v.z;
  if (base < N)     { row_start[base] = e0;     cursor[base] = e0; }
  if (base + 1 < N) { row_start[base + 1] = e1; cursor[base + 1] = e1; }
  if (base + 2 < N) { row_start[base + 2] = e2; cursor[base + 2] = e2; }
  if (base + 3 < N) { row_start[base + 3] = e3; cursor[base + 3] = e3; }
}

__global__ void k_scatter(const int* __restrict__ ei, const int* __restrict__ combo,
                          int* cursor, int* packed, int E) {
  int e = blockIdx.x * blockDim.x + threadIdx.x;
  if (e >= E) return;
  int s = ei[e], d = ei[E + e];
  int cb = combo[e];
  int pos = atomicAdd(&cursor[d], 1);
  packed[pos] = s | (cb << 20);  // src < 2^20, combo in [0,12)
}

// ---------------- fragment-ordered weights + bond table + h0 (merged) ----------------
// W1F: per (c,ks,nt,lane) 16B frag in the exact order k_mlp's GEMM1 reads.
//   entry e = ((c*4+ks)*4+nt)*64+lane; lane=(q<<4)|lo; n=c*64+nt*16+lo; k=(ks*4+q)*8+j
// W2F: entry e = ((c*2+ks2)*8+nt)*64+lane; n2=nt*16+lo; k2=c*64+(ks2*4+q)*8+j
__global__ void k_prep(const float* __restrict__ cflt, const int* __restrict__ x,
                       u32* __restrict__ W1F, u32* __restrict__ W2F,
                       u32* __restrict__ tblC, u32* __restrict__ hb, int N, int wtBlocks) {
  if ((int)blockIdx.x < wtBlocks) {
    const float* W1 = cflt + 16512;   // [128][256] row-major (k, n)
    const float* W2 = cflt + 49536;   // [256][128] row-major (k2, n2)
    const float* bt = cflt + 15616;
    const float* bd = cflt + 16128;
    int g = blockIdx.x * 256 + threadIdx.x;  // 0..16383 (one u32 of each table)
    {
      int e = g >> 2, wd = g & 3;
      int lane = e & 63, nt = (e >> 6) & 3, ks = (e >> 8) & 3, c = (e >> 10) & 3;
      int q = lane >> 4, lo = lane & 15;
      int n = c * 64 + nt * 16 + lo;
      int k0 = (ks * 4 + q) * 8 + wd * 2;
      W1F[g] = pk2(W1[k0 * 256 + n], W1[(k0 + 1) * 256 + n]);
    }
    {
      int e = g >> 2, wd = g & 3;
      int lane = e & 63, nt = (e >> 6) & 7, ks2 = (e >> 9) & 1, c = (e >> 10) & 3;
      int q = lane >> 4, lo = lane & 15;
      int n2 = nt * 16 + lo;
      int k20 = c * 64 + (ks2 * 4 + q) * 8 + wd * 2;
      W2F[g] = pk2(W2[k20 * 128 + n2], W2[(k20 + 1) * 128 + n2]);
    }
    if (g < 768) {
      int combo = g >> 6, l = g & 63, c0 = l * 2;
      int a0 = combo / 3, a1 = combo - a0 * 3;
      tblC[g] = pk2(bt[a0 * 128 + c0] + bd[a1 * 128 + c0],
                    bt[a0 * 128 + c0 + 1] + bd[a1 * 128 + c0 + 1]);
    }
  } else {
    const float* elem = cflt;
    const float* chir = cflt + 15104;
    int b = blockIdx.x - wtBlocks;
    int wv = (int)(threadIdx.x >> 6);
    int lane = threadIdx.x & 63;
    int node = b * 4 + wv;
    if (node >= N) return;
    int x0 = x[node * 2], x1 = x[node * 2 + 1];
    int c0 = lane * 2;
    float vx = elem[x0 * 128 + c0] + chir[x1 * 128 + c0];
    float vy = elem[x0 * 128 + c0 + 1] + chir[x1 * 128 + c0 + 1];
    hb[(size_t)node * 64 + lane] = pk2(vx, vy);
  }
}

// ---------------- gather/aggregate (pure; BN pre-applied in hb) ----------------
__global__ __launch_bounds__(256) void k_agg(
    const u32* __restrict__ hb, const int* __restrict__ row_start,
    const int* __restrict__ packed, const u32* __restrict__ tblC,
    u32* __restrict__ z, int N, int Mpad) {
  __shared__ u32 tbl[768];
  for (int idx = threadIdx.x; idx < 768; idx += 256) tbl[idx] = tblC[idx];
  __syncthreads();
  int wv = __builtin_amdgcn_readfirstlane((int)(threadIdx.x >> 6));
  int lane = threadIdx.x & 63;
  int node = blockIdx.x * 4 + wv;
  if (node >= Mpad) return;
  if (node >= N) { z[(size_t)node * 64 + lane] = 0u; return; }
  float2 sv = up2(hb[(size_t)node * 64 + lane]);
  float accx = sv.x, accy = sv.y;  // z = h + sum(msg)
  int s_ = row_start[node], e_ = row_start[node + 1];
  int p = s_;
  for (; p + 4 <= e_; p += 4) {
    int k0 = packed[p], k1 = packed[p + 1], k2 = packed[p + 2], k3 = packed[p + 3];
    u32 r0 = hb[(size_t)(k0 & 0xFFFFF) * 64 + lane];
    u32 r1 = hb[(size_t)(k1 & 0xFFFFF) * 64 + lane];
    u32 r2 = hb[(size_t)(k2 & 0xFFFFF) * 64 + lane];
    u32 r3 = hb[(size_t)(k3 & 0xFFFFF) * 64 + lane];
    u32 t0 = tbl[(k0 >> 20) * 64 + lane];
    u32 t1 = tbl[(k1 >> 20) * 64 + lane];
    u32 t2 = tbl[(k2 >> 20) * 64 + lane];
    u32 t3 = tbl[(k3 >> 20) * 64 + lane];
    h2 m0 = relu2(asH2(r0) + asH2(t0));
    h2 m1 = relu2(asH2(r1) + asH2(t1));
    h2 m2 = relu2(asH2(r2) + asH2(t2));
    h2 m3 = relu2(asH2(r3) + asH2(t3));
    accx += (float)m0.x + (float)m1.x + (float)m2.x + (float)m3.x;
    accy += (float)m0.y + (float)m1.y + (float)m2.y + (float)m3.y;
  }
  for (; p < e_; ++p) {
    int k0 = packed[p];
    u32 r0 = hb[(size_t)(k0 & 0xFFFFF) * 64 + lane];
    u32 t0 = tbl[(k0 >> 20) * 64 + lane];
    h2 m0 = relu2(asH2(r0) + asH2(t0));
    accx += (float)m0.x;
    accy += (float)m0.y;
  }
  z[(size_t)node * 64 + lane] = pk2(accx, accy);
}

// ---------------- barrier-free fused MLP + BN-stat partials ----------------
// 32-row tiles, 128-thread blocks (2 waves), grid ~1564 for TLP.
// W frags: fragment-ordered global (1KB contiguous per wave-load, L1/L2-hot),
// batched 16 loads before each MFMA burst. Y via wave-private LDS (no barriers).
__global__ __launch_bounds__(128, 3) void k_mlp(
    const u16* __restrict__ z, const u32* __restrict__ W1F, const u32* __restrict__ W2F,
    const float* __restrict__ b1, const float* __restrict__ b2,
    u16* __restrict__ act, float* __restrict__ statsL, int N) {
  __shared__ u16 sZ[32 * 128];       // 8KB shared Z tile (swizzled)
  __shared__ u16 sYp[2][16 * 64];    // 4KB per-wave private Y
  __shared__ float sRed[2][2][128];  // 2KB

  const int tid = threadIdx.x;
  const int w = tid >> 6, lane = tid & 63;
  const int lo = lane & 15, q = lane >> 4;
  const int row0 = blockIdx.x * 32;

  // stage Z tile (coalesced 16B, XOR-swizzled): 8KB via 128 thr x 16B x 4
#pragma unroll
  for (int t = 0; t < 4; ++t) {
    int L = t * 2048 + tid * 16;
    int row = L >> 8, slot = (L >> 4) & 15;
    int kb = slot ^ (row & 15);
    *(int4*)((char*)sZ + L) =
        *(const int4*)((const char*)z + (size_t)(row0 + row) * 256 + kb * 16);
  }
  __syncthreads();  // the only data barrier

  // A1-fragments for this wave's 16 rows (full K=128)
  const int rw = w * 16 + lo;
  f16x8 a1[4];
#pragma unroll
  for (int ks = 0; ks < 4; ++ks) {
    int kq = ks * 4 + q;
    a1[ks] = *(const f16x8*)(sZ + rw * 128 + ((kq ^ lo) << 3));
  }

  u16* myY = sYp[w];
  f32x4 accO[8] = {};
#pragma unroll
  for (int c = 0; c < 4; ++c) {
    // batched B1 loads: 16 contiguous 1KB wave-loads
    f16x8 B1[16];
#pragma unroll
    for (int i = 0; i < 16; ++i)
      B1[i] = *(const f16x8*)((const char*)W1F + ((c * 16 + i) << 10) + lane * 16);
    // GEMM1: Y[16 x 64] = Z[16 x 128] @ W1[:, c*64 : c*64+64)
    f32x4 acc1[4] = {};
#pragma unroll
    for (int ks = 0; ks < 4; ++ks)
#pragma unroll
      for (int nt = 0; nt < 4; ++nt)
        acc1[nt] = __builtin_amdgcn_mfma_f32_16x16x32_f16(a1[ks], B1[ks * 4 + nt], acc1[nt], 0, 0, 0);
    // bias + relu -> private Y (C-layout scatter, swizzled)
#pragma unroll
    for (int nt = 0; nt < 4; ++nt) {
      int ycol = nt * 16 + lo;
      float bias = b1[c * 64 + ycol];
#pragma unroll
      for (int i = 0; i < 4; ++i) {
        int m = q * 4 + i;
        float v = fmaxf(acc1[nt][i] + bias, 0.f);
        myY[m * 64 + (((ycol >> 3) ^ (m & 7)) << 3) + (ycol & 7)] = f2h_bits(v);
      }
    }
    // batched B2 loads (independent of Y writes -> overlaps lgkm wait)
    f16x8 B2[16];
#pragma unroll
    for (int i = 0; i < 16; ++i)
      B2[i] = *(const f16x8*)((const char*)W2F + ((c * 16 + i) << 10) + lane * 16);
    // GEMM2 partial: OUT += Y @ W2[c*64 : c*64+64, :]  (same-wave LDS dep only)
#pragma unroll
    for (int ks2 = 0; ks2 < 2; ++ks2) {
      int kq2 = ks2 * 4 + q;
      f16x8 a2 = *(const f16x8*)(myY + lo * 64 + ((kq2 ^ (lo & 7)) << 3));
#pragma unroll
      for (int nt = 0; nt < 8; ++nt)
        accO[nt] = __builtin_amdgcn_mfma_f32_16x16x32_f16(a2, B2[ks2 * 8 + nt], accO[nt], 0, 0, 0);
    }
  }

  // epilogue: +b2, f16 store, BN-stat partials
#pragma unroll
  for (int nt = 0; nt < 8; ++nt) {
    int n2 = nt * 16 + lo;
    float bias = b2[n2];
    float ssum = 0.f, ssq = 0.f;
#pragma unroll
    for (int i = 0; i < 4; ++i) {
      int row = row0 + w * 16 + q * 4 + i;
      float v = accO[nt][i] + bias;
      act[(size_t)row * 128 + n2] = f2h_bits(v);
      if (row < N) { ssum += v; ssq += v * v; }
    }
    ssum += __shfl_xor(ssum, 16); ssum += __shfl_xor(ssum, 32);
    ssq  += __shfl_xor(ssq, 16);  ssq  += __shfl_xor(ssq, 32);
    if (q == 0) { sRed[w][0][n2] = ssum; sRed[w][1][n2] = ssq; }
  }
  __syncthreads();
  {
    int col = tid;  // 0..127
    atomicAdd(&statsL[col],       sRed[0][0][col] + sRed[1][0][col]);
    atomicAdd(&statsL[128 + col], sRed[0][1][col] + sRed[1][1][col]);
  }
}

// ---------------- BN apply + relu (per node, computes sc/sh in-block) ----------------
__global__ __launch_bounds__(256) void k_bnapply(
    const u32* __restrict__ act, const float* __restrict__ statsL,
    const float* __restrict__ gamma, const float* __restrict__ beta,
    float invN, u32* __restrict__ hb, int N) {
  __shared__ float ssc[128], ssh[128];
  int tid = threadIdx.x;
  if (tid < 128) {
    float mean = statsL[tid] * invN;
    float var = statsL[128 + tid] * invN - mean * mean;
    float inv = rsqrtf(var + 1e-5f);
    float scv = gamma[tid] * inv;
    ssc[tid] = scv;
    ssh[tid] = beta[tid] - mean * scv;
  }
  __syncthreads();
  int total = N * 64;
  for (int i = blockIdx.x * 256 + tid; i < total; i += gridDim.x * 256) {
    int c0 = (i & 63) * 2;
    float2 v = up2(act[i]);
    float ox = fmaxf(v.x * ssc[c0] + ssh[c0], 0.f);
    float oy = fmaxf(v.y * ssc[c0 + 1] + ssh[c0 + 1], 0.f);
    hb[i] = pk2(ox, oy);
  }
}

// ---------------- final: BN (no relu) -> output dtype ----------------
__global__ __launch_bounds__(256) void k_final(
    const u32* __restrict__ act, const float* __restrict__ statsL,
    const float* __restrict__ gamma, const float* __restrict__ beta,
    float invN, const int* __restrict__ dflags, void* __restrict__ outv, int N) {
  __shared__ float ssc[128], ssh[128];
  int tid = threadIdx.x;
  if (tid < 128) {
    float mean = statsL[tid] * invN;
    float var = statsL[128 + tid] * invN - mean * mean;
    float inv = rsqrtf(var + 1e-5f);
    float scv = gamma[tid] * inv;
    ssc[tid] = scv;
    ssh[tid] = beta[tid] - mean * scv;
  }
  __syncthreads();
  int isbf = dflags[0];
  int total = N * 64;
  for (int i = blockIdx.x * 256 + tid; i < total; i += gridDim.x * 256) {
    int c0 = (i & 63) * 2;
    float2 v = up2(act[i]);
    float ox = v.x * ssc[c0] + ssh[c0];
    float oy = v.y * ssc[c0 + 1] + ssh[c0 + 1];
    if (isbf) ((u32*)outv)[i] = (u32)f2bf(ox) | ((u32)f2bf(oy) << 16);
    else { float2 o; o.x = ox; o.y = oy; ((float2*)outv)[i] = o; }
  }
}

extern "C" void kernel_launch(void* const* d_in, const int* in_sizes, int n_in,
                              void* d_out, int out_size, void* d_ws, size_t ws_size,
                              hipStream_t stream) {
  const int* xR  = (const int*)d_in[0];
  const int* eiR = (const int*)d_in[1];
  const int* eaR = (const int*)d_in[2];
  const u16* emR = (const u16*)d_in[3];
  const u16* chR = (const u16*)d_in[4];
  const u16* btR = (const u16*)d_in[5];
  const u16* bdR = (const u16*)d_in[6];
  const u16* W1R = (const u16*)d_in[7];
  const u16* b1R = (const u16*)d_in[8];
  const u16* W2R = (const u16*)d_in[9];
  const u16* b2R = (const u16*)d_in[10];
  const u16* gR  = (const u16*)d_in[11];
  const u16* beR = (const u16*)d_in[12];

  const int N = in_sizes[0] / 2;      // 50000
  const int E = in_sizes[1] / 2;      // 600000
  const int L = in_sizes[11] / 128;   // 5
  const int Mpad = ((N + 63) / 64) * 64;
  const int nCh = (N + 1023) / 1024;
  const int NPad = nCh * 1024;

  char* base = (char*)d_ws;
  size_t off = 0;
  auto take = [&](size_t bytes) -> void* {
    void* p = base + off;
    off += (bytes + 255) & ~(size_t)255;
    return p;
  };
  int*   dflags    = (int*)  take(256);
  int*   x32       = (int*)  take((size_t)2 * N * 4);
  int*   ei32      = (int*)  take((size_t)2 * E * 4);
  int*   combo     = (int*)  take((size_t)E * 4);
  float* cflt      = (float*)take(83712 * 4);
  u32*   act       = (u32*)  take((size_t)Mpad * 64 * 4);   // raw MLP out (f16 pairs)
  u32*   hb        = (u32*)  take((size_t)Mpad * 64 * 4);   // BN-applied relu'd h
  u16*   zb        = (u16*)  take((size_t)Mpad * 128 * 2);
  int*   packed    = (int*)  take((size_t)E * 4);
  int*   row_start = (int*)  take((size_t)(N + 1) * 4);
  int*   cursor    = (int*)  take((size_t)N * 4);
  int*   counts    = (int*)  take((size_t)NPad * 4);
  int*   bsum      = (int*)  take(64 * 4);
  int*   boff      = (int*)  take(64 * 4);
  float* stats     = (float*)take((size_t)L * 256 * 4);
  u32*   W1F       = (u32*)  take(16384 * 4);
  u32*   W2F       = (u32*)  take(16384 * 4);
  u32*   tblC      = (u32*)  take(768 * 4);
  const size_t need = off;
  (void)n_in;

  float* cB1 = cflt + 49280;
  float* cB2 = cflt + 82304;
  float* cGamma = cflt + 82432;
  float* cBeta = cflt + 83072;

  k_detect<<<dim3(1), dim3(256), 0, stream>>>(emR, eiR, dflags);

  if (need > ws_size) {
    k_canary<<<dim3((out_size + 255) / 256), dim3(256), 0, stream>>>(
        (u32*)d_out, dflags, out_size, 0x40004000u, 0x40000000u);
    return;
  }

  k_zero<<<dim3((NPad + 1280 + 255) / 256), dim3(256), 0, stream>>>(counts, stats, NPad);

  const int nPairs = N + 2 * E;
  const int intBlocks = (nPairs + 255) / 256;
  const int fltBlocks = (83712 + 255) / 256;
  k_cvt<<<dim3(intBlocks + fltBlocks), dim3(256), 0, stream>>>(
      xR, eiR, eaR, emR, chR, btR, bdR, W1R, b1R, W2R, b2R, gR, beR,
      dflags, x32, ei32, combo, counts, cflt, N, E, intBlocks);

  k_chunksum<<<dim3(nCh), dim3(256), 0, stream>>>(counts, bsum);
  k_chunkscan<<<dim3(1), dim3(64), 0, stream>>>(bsum, boff, row_start, N, nCh);
  k_scanapply<<<dim3(nCh), dim3(256), 0, stream>>>(counts, boff, row_start, cursor, N);
  k_scatter<<<dim3((E + 255) / 256), dim3(256), 0, stream>>>(ei32, combo, cursor, packed, E);

  const int wtBlocks = 64;  // 16384 threads for W1F/W2F words
  k_prep<<<dim3(wtBlocks + (N + 3) / 4), dim3(256), 0, stream>>>(
      cflt, x32, W1F, W2F, tblC, hb, N, wtBlocks);

  const float invN = 1.0f / (float)N;
  for (int l = 0; l < L; ++l) {
    k_agg<<<dim3(Mpad / 4), dim3(256), 0, stream>>>(
        hb, row_start, packed, tblC, (u32*)zb, N, Mpad);
    k_mlp<<<dim3(Mpad / 32), dim3(128), 0, stream>>>(
        zb, W1F, W2F, cB1, cB2, (u16*)act, stats + (size_t)l * 256, N);
    if (l < L - 1) {
      k_bnapply<<<dim3(1024), dim3(256), 0, stream>>>(
          act, stats + (size_t)l * 256, cGamma + (size_t)l * 128, cBeta + (size_t)l * 128,
          invN, hb, N);
    }
  }
  k_final<<<dim3(1024), dim3(256), 0, stream>>>(
      act, stats + (size_t)(L - 1) * 256, cGamma + (size_t)(L - 1) * 128,
      cBeta + (size_t)(L - 1) * 128, invN, dflags, d_out, N);
}

// Round 9
// 471.229 us; speedup vs baseline: 1.5864x; 1.3789x over previous
//
#include <hip/hip_runtime.h>

typedef _Float16 f16;
typedef _Float16 f16x8 __attribute__((ext_vector_type(8)));
typedef _Float16 h2 __attribute__((ext_vector_type(2)));
typedef float f32x4 __attribute__((ext_vector_type(4)));
typedef unsigned short u16;
typedef unsigned int u32;

// ---------- conversions ----------
__device__ __forceinline__ float bf2f(u16 b) {
  union { u32 u; float f; } t; t.u = ((u32)b) << 16; return t.f;
}
__device__ __forceinline__ u16 f2bf(float f) {  // RNE float->bf16 bits
  union { float f; u32 u; } t; t.f = f;
  u32 u = t.u;
  return (u16)((u + 0x7FFFu + ((u >> 16) & 1u)) >> 16);
}
__device__ __forceinline__ u16 f2h_bits(float f) {
  f16 h = (f16)f;
  union { f16 h; u16 u; } t; t.h = h; return t.u;
}
__device__ __forceinline__ float2 up2(u32 p) {  // f16 pair -> float2
  union { u32 u; f16 h[2]; } t; t.u = p;
  float2 r; r.x = (float)t.h[0]; r.y = (float)t.h[1]; return r;
}
__device__ __forceinline__ u32 pk2(float x, float y) {  // float2 -> f16 pair
  return (u32)f2h_bits(x) | ((u32)f2h_bits(y) << 16);
}
__device__ __forceinline__ h2 asH2(u32 u) {
  union { u32 u; h2 h; } t; t.u = u; return t.h;
}
__device__ __forceinline__ h2 relu2(h2 a) {
#if __has_builtin(__builtin_elementwise_max)
  h2 z = {(_Float16)0, (_Float16)0};
  return __builtin_elementwise_max(a, z);
#else
  h2 r;
  r.x = a.x > (_Float16)0 ? a.x : (_Float16)0;
  r.y = a.y > (_Float16)0 ? a.y : (_Float16)0;
  return r;
#endif
}

// ---------------- dtype detection ----------------
__global__ void k_detect(const u16* __restrict__ elemRaw, const int* __restrict__ eiRaw,
                         int* __restrict__ dflags) {
  __shared__ int bad, nzOdd;
  if (threadIdx.x == 0) { bad = 0; nzOdd = 0; }
  __syncthreads();
  int myBad = 0;
  for (int i = threadIdx.x; i < 4096; i += 256) {
    float v = bf2f(elemRaw[i]);
    if (!(v > -0.2f && v < 0.2f)) myBad++;
  }
  if (myBad) atomicAdd(&bad, myBad);
  int myNz = 0;
  for (int i = threadIdx.x; i < 1024; i += 256)
    if (eiRaw[2 * i + 1] != 0) myNz++;  // int64 high words would be 0
  if (myNz) atomicAdd(&nzOdd, myNz);
  __syncthreads();
  if (threadIdx.x == 0) {
    dflags[0] = (bad == 0) ? 1 : 0;
    dflags[1] = (nzOdd > 16) ? 1 : 0;
  }
}

__global__ void k_canary(u32* __restrict__ out, const int* __restrict__ dflags,
                         int out_size, u32 pBf, u32 pF32) {
  int isbf = dflags[0];
  int words = isbf ? (out_size >> 1) : out_size;
  int i = blockIdx.x * 256 + threadIdx.x;
  if (i < words) out[i] = isbf ? pBf : pF32;
}

// ---------------- zero ----------------
__global__ void k_zero(int* counts, float* stats, int NPad) {
  int i = blockIdx.x * blockDim.x + threadIdx.x;
  if (i < NPad) counts[i] = 0;
  else if (i < NPad + 1280) stats[i - NPad] = 0.f;
}

// ---------------- combined canonicalize (+fused dst histogram) ----------------
__global__ void k_cvt(const int* __restrict__ xR, const int* __restrict__ eiR,
                      const int* __restrict__ eaR,
                      const u16* e0, const u16* e1, const u16* e2, const u16* e3,
                      const u16* e4, const u16* e5, const u16* e6, const u16* e7,
                      const u16* e8, const u16* e9,
                      const int* __restrict__ dflags,
                      int* __restrict__ x32, int* __restrict__ ei32, int* __restrict__ combo,
                      int* __restrict__ counts, float* __restrict__ dst,
                      int N, int E, int intBlocks) {
  if ((int)blockIdx.x < intBlocks) {
    int pi = blockIdx.x * 256 + threadIdx.x;
    int nPairs = N + 2 * E;
    if (pi >= nPairs) return;
    int is32 = dflags[1];
    const int* src; int local; int kind;
    if (pi < N) { src = xR; local = pi; kind = 0; }
    else if (pi < N + E) { src = eiR; local = pi - N; kind = 1; }
    else { src = eaR; local = pi - N - E; kind = 2; }
    int j0 = 2 * local;
    int v0, v1;
    if (is32) { int2 v = *(const int2*)(src + j0); v0 = v.x; v1 = v.y; }
    else      { int4 v = *(const int4*)(src + 2 * j0); v0 = v.x; v1 = v.z; }
    if (kind == 0) { x32[j0] = v0; x32[j0 + 1] = v1; }
    else if (kind == 1) {
      ei32[j0] = v0; ei32[j0 + 1] = v1;
      if (j0 >= E) {  // dst half
        atomicAdd(&counts[v0], 1);
        atomicAdd(&counts[v1], 1);
      }
    } else {
      combo[local] = v0 * 3 + v1;
    }
  } else {
    int i = (blockIdx.x - intBlocks) * 256 + threadIdx.x;
    if (i >= 83712) return;
    int isbf = dflags[0];
    const u16* src; int j;
    if      (i < 15104) { src = e0; j = i; }
    else if (i < 15616) { src = e1; j = i - 15104; }
    else if (i < 16128) { src = e2; j = i - 15616; }
    else if (i < 16512) { src = e3; j = i - 16128; }
    else if (i < 49280) { src = e4; j = i - 16512; }
    else if (i < 49536) { src = e5; j = i - 49280; }
    else if (i < 82304) { src = e6; j = i - 49536; }
    else if (i < 82432) { src = e7; j = i - 82304; }
    else if (i < 83072) { src = e8; j = i - 82432; }
    else                { src = e9; j = i - 83072; }
    dst[i] = isbf ? bf2f(src[j]) : ((const float*)src)[j];
  }
}

// ---------------- CSR scan ----------------
__global__ void k_chunksum(const int* __restrict__ counts, int* __restrict__ bsum) {
  int tid = threadIdx.x, lane = tid & 63, w = tid >> 6;
  const int4* c4 = (const int4*)(counts + blockIdx.x * 1024);
  int4 v = c4[tid];
  int s = v.x + v.y + v.z + v.w;
#pragma unroll
  for (int d = 1; d < 64; d <<= 1) s += __shfl_xor(s, d);
  __shared__ int ws[4];
  if (lane == 0) ws[w] = s;
  __syncthreads();
  if (tid == 0) bsum[blockIdx.x] = ws[0] + ws[1] + ws[2] + ws[3];
}

__global__ void k_chunkscan(const int* __restrict__ bsum, int* __restrict__ boff,
                            int* __restrict__ row_start, int N, int nCh) {
  int t = threadIdx.x;
  int v = (t < nCh) ? bsum[t] : 0;
  int incl = v;
#pragma unroll
  for (int d = 1; d < 64; d <<= 1) { int tmp = __shfl_up(incl, d); if (t >= d) incl += tmp; }
  boff[t] = incl - v;
  if (t == 63) row_start[N] = incl;  // = E
}

__global__ void k_scanapply(const int* __restrict__ counts, const int* __restrict__ boff,
                            int* __restrict__ row_start, int* __restrict__ cursor, int N) {
  int tid = threadIdx.x, lane = tid & 63, w = tid >> 6;
  int base = blockIdx.x * 1024 + tid * 4;
  int4 v = *(const int4*)(counts + base);
  int tsum = v.x + v.y + v.z + v.w;
  int incl = tsum;
#pragma unroll
  for (int d = 1; d < 64; d <<= 1) { int tmp = __shfl_up(incl, d); if (lane >= d) incl += tmp; }
  __shared__ int ws[4];
  if (lane == 63) ws[w] = incl;
  __syncthreads();
  int woff = 0;
  for (int j = 0; j < w; ++j) woff += ws[j];
  int excl = boff[blockIdx.x] + woff + incl - tsum;
  int e0 = excl, e1 = excl + v.x, e2 = e1 + v.y, e3 = e2 + v.z;
  if (base < N)     { row_start[base] = e0;     cursor[base] = e0; }
  if (base + 1 < N) { row_start[base + 1] = e1; cursor[base + 1] = e1; }
  if (base + 2 < N) { row_start[base + 2] = e2; cursor[base + 2] = e2; }
  if (base + 3 < N) { row_start[base + 3] = e3; cursor[base + 3] = e3; }
}

__global__ void k_scatter(const int* __restrict__ ei, const int* __restrict__ combo,
                          int* cursor, int* packed, int E) {
  int e = blockIdx.x * blockDim.x + threadIdx.x;
  if (e >= E) return;
  int s = ei[e], d = ei[E + e];
  int cb = combo[e];
  int pos = atomicAdd(&cursor[d], 1);
  packed[pos] = s | (cb << 20);  // src < 2^20, combo in [0,12)
}

// ---------------- fragment-ordered weights + bond table + h0 (merged) ----------------
// W1F: per (c,ks,nt,lane) 16B frag in the exact order k_mlp's GEMM1 reads.
// W2F: entry e = ((c*2+ks2)*8+nt)*64+lane; n2=nt*16+lo; k2=c*64+(ks2*4+q)*8+j
__global__ void k_prep(const float* __restrict__ cflt, const int* __restrict__ x,
                       u32* __restrict__ W1F, u32* __restrict__ W2F,
                       u32* __restrict__ tblC, u32* __restrict__ hb, int N, int wtBlocks) {
  if ((int)blockIdx.x < wtBlocks) {
    const float* W1 = cflt + 16512;   // [128][256] row-major (k, n)
    const float* W2 = cflt + 49536;   // [256][128] row-major (k2, n2)
    const float* bt = cflt + 15616;
    const float* bd = cflt + 16128;
    int g = blockIdx.x * 256 + threadIdx.x;  // 0..16383 (one u32 of each table)
    {
      int e = g >> 2, wd = g & 3;
      int lane = e & 63, nt = (e >> 6) & 3, ks = (e >> 8) & 3, c = (e >> 10) & 3;
      int q = lane >> 4, lo = lane & 15;
      int n = c * 64 + nt * 16 + lo;
      int k0 = (ks * 4 + q) * 8 + wd * 2;
      W1F[g] = pk2(W1[k0 * 256 + n], W1[(k0 + 1) * 256 + n]);
    }
    {
      int e = g >> 2, wd = g & 3;
      int lane = e & 63, nt = (e >> 6) & 7, ks2 = (e >> 9) & 1, c = (e >> 10) & 3;
      int q = lane >> 4, lo = lane & 15;
      int n2 = nt * 16 + lo;
      int k20 = c * 64 + (ks2 * 4 + q) * 8 + wd * 2;
      W2F[g] = pk2(W2[k20 * 128 + n2], W2[(k20 + 1) * 128 + n2]);
    }
    if (g < 768) {
      int combo = g >> 6, l = g & 63, c0 = l * 2;
      int a0 = combo / 3, a1 = combo - a0 * 3;
      tblC[g] = pk2(bt[a0 * 128 + c0] + bd[a1 * 128 + c0],
                    bt[a0 * 128 + c0 + 1] + bd[a1 * 128 + c0 + 1]);
    }
  } else {
    const float* elem = cflt;
    const float* chir = cflt + 15104;
    int b = blockIdx.x - wtBlocks;
    int wv = (int)(threadIdx.x >> 6);
    int lane = threadIdx.x & 63;
    int node = b * 4 + wv;
    if (node >= N) return;
    int x0 = x[node * 2], x1 = x[node * 2 + 1];
    int c0 = lane * 2;
    float vx = elem[x0 * 128 + c0] + chir[x1 * 128 + c0];
    float vy = elem[x0 * 128 + c0 + 1] + chir[x1 * 128 + c0 + 1];
    hb[(size_t)node * 64 + lane] = pk2(vx, vy);
  }
}

// ---------------- gather/aggregate (pure; BN pre-applied in hb) ----------------
__global__ __launch_bounds__(256) void k_agg(
    const u32* __restrict__ hb, const int* __restrict__ row_start,
    const int* __restrict__ packed, const u32* __restrict__ tblC,
    u32* __restrict__ z, int N) {
  __shared__ u32 tbl[768];
  for (int idx = threadIdx.x; idx < 768; idx += 256) tbl[idx] = tblC[idx];
  __syncthreads();
  int wv = __builtin_amdgcn_readfirstlane((int)(threadIdx.x >> 6));
  int lane = threadIdx.x & 63;
  int node = blockIdx.x * 4 + wv;
  if (node >= N) return;
  float2 sv = up2(hb[(size_t)node * 64 + lane]);
  float accx = sv.x, accy = sv.y;  // z = h + sum(msg)
  int s_ = row_start[node], e_ = row_start[node + 1];
  int p = s_;
  for (; p + 4 <= e_; p += 4) {
    int k0 = packed[p], k1 = packed[p + 1], k2 = packed[p + 2], k3 = packed[p + 3];
    u32 r0 = hb[(size_t)(k0 & 0xFFFFF) * 64 + lane];
    u32 r1 = hb[(size_t)(k1 & 0xFFFFF) * 64 + lane];
    u32 r2 = hb[(size_t)(k2 & 0xFFFFF) * 64 + lane];
    u32 r3 = hb[(size_t)(k3 & 0xFFFFF) * 64 + lane];
    u32 t0 = tbl[(k0 >> 20) * 64 + lane];
    u32 t1 = tbl[(k1 >> 20) * 64 + lane];
    u32 t2 = tbl[(k2 >> 20) * 64 + lane];
    u32 t3 = tbl[(k3 >> 20) * 64 + lane];
    h2 m0 = relu2(asH2(r0) + asH2(t0));
    h2 m1 = relu2(asH2(r1) + asH2(t1));
    h2 m2 = relu2(asH2(r2) + asH2(t2));
    h2 m3 = relu2(asH2(r3) + asH2(t3));
    accx += (float)m0.x + (float)m1.x + (float)m2.x + (float)m3.x;
    accy += (float)m0.y + (float)m1.y + (float)m2.y + (float)m3.y;
  }
  for (; p < e_; ++p) {
    int k0 = packed[p];
    u32 r0 = hb[(size_t)(k0 & 0xFFFFF) * 64 + lane];
    u32 t0 = tbl[(k0 >> 20) * 64 + lane];
    h2 m0 = relu2(asH2(r0) + asH2(t0));
    accx += (float)m0.x;
    accy += (float)m0.y;
  }
  z[(size_t)node * 64 + lane] = pk2(accx, accy);
}

// ---------------- persistent MLP: weights LDS-resident, one block per CU ----------------
// grid=256 x 512 thr. Weights staged global->LDS ONCE (128 KB), B-frags from LDS.
// Z A-frags read directly from global (row-independent MFMA). No barriers in tile loop.
__global__ __launch_bounds__(512, 2) void k_mlp(
    const u16* __restrict__ z, const u32* __restrict__ W1F, const u32* __restrict__ W2F,
    const float* __restrict__ b1, const float* __restrict__ b2,
    u16* __restrict__ act, float* __restrict__ statsL, int N, int nTiles) {
  __shared__ u32 sW1[16384];     // 64 KB fragment-ordered W1
  __shared__ u32 sW2[16384];     // 64 KB fragment-ordered W2
  __shared__ u16 sYp[8][1024];   // 16 KB: per-wave private Y (16x64, swizzled)
  __shared__ float sStats[256];  // 1 KB

  const int tid = threadIdx.x;
  const int w = tid >> 6, lane = tid & 63;
  const int lo = lane & 15, q = lane >> 4;

  if (tid < 256) sStats[tid] = 0.f;
  // stage both weight tables: 512 thr x 16 B x 8 iters each
  {
    const int4* gW1 = (const int4*)W1F;
    const int4* gW2 = (const int4*)W2F;
    int4* lW1 = (int4*)sW1;
    int4* lW2 = (int4*)sW2;
#pragma unroll
    for (int it = 0; it < 8; ++it) {
      int o = it * 512 + tid;
      lW1[o] = gW1[o];
      lW2[o] = gW2[o];
    }
  }
  __syncthreads();

  // bias preload (per-lane registers)
  float rb1[16], rb2[8];
#pragma unroll
  for (int c = 0; c < 4; ++c)
#pragma unroll
    for (int nt = 0; nt < 4; ++nt)
      rb1[c * 4 + nt] = b1[c * 64 + nt * 16 + lo];
#pragma unroll
  for (int nt = 0; nt < 8; ++nt)
    rb2[nt] = b2[nt * 16 + lo];

  float aSum[8] = {}, aSq[8] = {};
  u16* myY = sYp[w];

  for (int t = blockIdx.x * 8 + w; t < nTiles; t += 2048) {
    const int row0 = t * 16;
    // A-frags straight from global (16 rows x 64B segments, L2/L3-hot)
    f16x8 a1[4];
    const char* zrow = (const char*)z + (size_t)(row0 + lo) * 256;
#pragma unroll
    for (int ks = 0; ks < 4; ++ks)
      a1[ks] = *(const f16x8*)(zrow + (ks * 4 + q) * 16);

    f32x4 accO[8] = {};
#pragma unroll
    for (int c = 0; c < 4; ++c) {
      f16x8 B1[16];
#pragma unroll
      for (int i = 0; i < 16; ++i)
        B1[i] = *(const f16x8*)((const char*)sW1 + ((c * 16 + i) << 10) + lane * 16);
      f32x4 acc1[4] = {};
#pragma unroll
      for (int ks = 0; ks < 4; ++ks)
#pragma unroll
        for (int nt = 0; nt < 4; ++nt)
          acc1[nt] = __builtin_amdgcn_mfma_f32_16x16x32_f16(a1[ks], B1[ks * 4 + nt], acc1[nt], 0, 0, 0);
      // bias + relu -> private Y (C->A transform, swizzled; same-wave only)
#pragma unroll
      for (int nt = 0; nt < 4; ++nt) {
        int ycol = nt * 16 + lo;
        float bias = rb1[c * 4 + nt];
#pragma unroll
        for (int i = 0; i < 4; ++i) {
          int m = q * 4 + i;
          float v = fmaxf(acc1[nt][i] + bias, 0.f);
          myY[m * 64 + (((ycol >> 3) ^ (m & 7)) << 3) + (ycol & 7)] = f2h_bits(v);
        }
      }
      f16x8 B2[16];
#pragma unroll
      for (int i = 0; i < 16; ++i)
        B2[i] = *(const f16x8*)((const char*)sW2 + ((c * 16 + i) << 10) + lane * 16);
#pragma unroll
      for (int ks2 = 0; ks2 < 2; ++ks2) {
        int kq2 = ks2 * 4 + q;
        f16x8 a2 = *(const f16x8*)(myY + lo * 64 + ((kq2 ^ (lo & 7)) << 3));
#pragma unroll
        for (int nt = 0; nt < 8; ++nt)
          accO[nt] = __builtin_amdgcn_mfma_f32_16x16x32_f16(a2, B2[ks2 * 8 + nt], accO[nt], 0, 0, 0);
      }
    }
    // epilogue: +b2, f16 store, per-lane stat accumulation
#pragma unroll
    for (int nt = 0; nt < 8; ++nt) {
      int n2 = nt * 16 + lo;
      float bias = rb2[nt];
#pragma unroll
      for (int i = 0; i < 4; ++i) {
        int row = row0 + q * 4 + i;
        float v = accO[nt][i] + bias;
        act[(size_t)row * 128 + n2] = f2h_bits(v);
        if (row < N) { aSum[nt] += v; aSq[nt] += v * v; }
      }
    }
  }

  // stats: reduce over q (same n2), LDS atomic, then one global flush per block
#pragma unroll
  for (int nt = 0; nt < 8; ++nt) {
    float s = aSum[nt], s2 = aSq[nt];
    s += __shfl_xor(s, 16); s += __shfl_xor(s, 32);
    s2 += __shfl_xor(s2, 16); s2 += __shfl_xor(s2, 32);
    if (q == 0) {
      atomicAdd(&sStats[nt * 16 + lo], s);
      atomicAdd(&sStats[128 + nt * 16 + lo], s2);
    }
  }
  __syncthreads();
  if (tid < 256) atomicAdd(&statsL[tid], sStats[tid]);
}

// ---------------- BN apply + relu (per node, computes sc/sh in-block) ----------------
__global__ __launch_bounds__(256) void k_bnapply(
    const u32* __restrict__ act, const float* __restrict__ statsL,
    const float* __restrict__ gamma, const float* __restrict__ beta,
    float invN, u32* __restrict__ hb, int N) {
  __shared__ float ssc[128], ssh[128];
  int tid = threadIdx.x;
  if (tid < 128) {
    float mean = statsL[tid] * invN;
    float var = statsL[128 + tid] * invN - mean * mean;
    float inv = rsqrtf(var + 1e-5f);
    float scv = gamma[tid] * inv;
    ssc[tid] = scv;
    ssh[tid] = beta[tid] - mean * scv;
  }
  __syncthreads();
  int total = N * 64;
  for (int i = blockIdx.x * 256 + tid; i < total; i += gridDim.x * 256) {
    int c0 = (i & 63) * 2;
    float2 v = up2(act[i]);
    float ox = fmaxf(v.x * ssc[c0] + ssh[c0], 0.f);
    float oy = fmaxf(v.y * ssc[c0 + 1] + ssh[c0 + 1], 0.f);
    hb[i] = pk2(ox, oy);
  }
}

// ---------------- final: BN (no relu) -> output dtype ----------------
__global__ __launch_bounds__(256) void k_final(
    const u32* __restrict__ act, const float* __restrict__ statsL,
    const float* __restrict__ gamma, const float* __restrict__ beta,
    float invN, const int* __restrict__ dflags, void* __restrict__ outv, int N) {
  __shared__ float ssc[128], ssh[128];
  int tid = threadIdx.x;
  if (tid < 128) {
    float mean = statsL[tid] * invN;
    float var = statsL[128 + tid] * invN - mean * mean;
    float inv = rsqrtf(var + 1e-5f);
    float scv = gamma[tid] * inv;
    ssc[tid] = scv;
    ssh[tid] = beta[tid] - mean * scv;
  }
  __syncthreads();
  int isbf = dflags[0];
  int total = N * 64;
  for (int i = blockIdx.x * 256 + tid; i < total; i += gridDim.x * 256) {
    int c0 = (i & 63) * 2;
    float2 v = up2(act[i]);
    float ox = v.x * ssc[c0] + ssh[c0];
    float oy = v.y * ssc[c0 + 1] + ssh[c0 + 1];
    if (isbf) ((u32*)outv)[i] = (u32)f2bf(ox) | ((u32)f2bf(oy) << 16);
    else { float2 o; o.x = ox; o.y = oy; ((float2*)outv)[i] = o; }
  }
}

extern "C" void kernel_launch(void* const* d_in, const int* in_sizes, int n_in,
                              void* d_out, int out_size, void* d_ws, size_t ws_size,
                              hipStream_t stream) {
  const int* xR  = (const int*)d_in[0];
  const int* eiR = (const int*)d_in[1];
  const int* eaR = (const int*)d_in[2];
  const u16* emR = (const u16*)d_in[3];
  const u16* chR = (const u16*)d_in[4];
  const u16* btR = (const u16*)d_in[5];
  const u16* bdR = (const u16*)d_in[6];
  const u16* W1R = (const u16*)d_in[7];
  const u16* b1R = (const u16*)d_in[8];
  const u16* W2R = (const u16*)d_in[9];
  const u16* b2R = (const u16*)d_in[10];
  const u16* gR  = (const u16*)d_in[11];
  const u16* beR = (const u16*)d_in[12];

  const int N = in_sizes[0] / 2;      // 50000
  const int E = in_sizes[1] / 2;      // 600000
  const int L = in_sizes[11] / 128;   // 5
  const int Mpad = ((N + 63) / 64) * 64;
  const int nCh = (N + 1023) / 1024;
  const int NPad = nCh * 1024;
  const int nTiles = (N + 15) / 16;   // 3125

  char* base = (char*)d_ws;
  size_t off = 0;
  auto take = [&](size_t bytes) -> void* {
    void* p = base + off;
    off += (bytes + 255) & ~(size_t)255;
    return p;
  };
  int*   dflags    = (int*)  take(256);
  int*   x32       = (int*)  take((size_t)2 * N * 4);
  int*   ei32      = (int*)  take((size_t)2 * E * 4);
  int*   combo     = (int*)  take((size_t)E * 4);
  float* cflt      = (float*)take(83712 * 4);
  u32*   act       = (u32*)  take((size_t)Mpad * 64 * 4);   // raw MLP out (f16 pairs)
  u32*   hb        = (u32*)  take((size_t)Mpad * 64 * 4);   // BN-applied relu'd h
  u16*   zb        = (u16*)  take((size_t)Mpad * 128 * 2);
  int*   packed    = (int*)  take((size_t)E * 4);
  int*   row_start = (int*)  take((size_t)(N + 1) * 4);
  int*   cursor    = (int*)  take((size_t)N * 4);
  int*   counts    = (int*)  take((size_t)NPad * 4);
  int*   bsum      = (int*)  take(64 * 4);
  int*   boff      = (int*)  take(64 * 4);
  float* stats     = (float*)take((size_t)L * 256 * 4);
  u32*   W1F       = (u32*)  take(16384 * 4);
  u32*   W2F       = (u32*)  take(16384 * 4);
  u32*   tblC      = (u32*)  take(768 * 4);
  const size_t need = off;
  (void)n_in;

  float* cB1 = cflt + 49280;
  float* cB2 = cflt + 82304;
  float* cGamma = cflt + 82432;
  float* cBeta = cflt + 83072;

  k_detect<<<dim3(1), dim3(256), 0, stream>>>(emR, eiR, dflags);

  if (need > ws_size) {
    k_canary<<<dim3((out_size + 255) / 256), dim3(256), 0, stream>>>(
        (u32*)d_out, dflags, out_size, 0x40004000u, 0x40000000u);
    return;
  }

  k_zero<<<dim3((NPad + 1280 + 255) / 256), dim3(256), 0, stream>>>(counts, stats, NPad);

  const int nPairs = N + 2 * E;
  const int intBlocks = (nPairs + 255) / 256;
  const int fltBlocks = (83712 + 255) / 256;
  k_cvt<<<dim3(intBlocks + fltBlocks), dim3(256), 0, stream>>>(
      xR, eiR, eaR, emR, chR, btR, bdR, W1R, b1R, W2R, b2R, gR, beR,
      dflags, x32, ei32, combo, counts, cflt, N, E, intBlocks);

  k_chunksum<<<dim3(nCh), dim3(256), 0, stream>>>(counts, bsum);
  k_chunkscan<<<dim3(1), dim3(64), 0, stream>>>(bsum, boff, row_start, N, nCh);
  k_scanapply<<<dim3(nCh), dim3(256), 0, stream>>>(counts, boff, row_start, cursor, N);
  k_scatter<<<dim3((E + 255) / 256), dim3(256), 0, stream>>>(ei32, combo, cursor, packed, E);

  const int wtBlocks = 64;  // 16384 threads for W1F/W2F words
  k_prep<<<dim3(wtBlocks + (N + 3) / 4), dim3(256), 0, stream>>>(
      cflt, x32, W1F, W2F, tblC, hb, N, wtBlocks);

  const float invN = 1.0f / (float)N;
  for (int l = 0; l < L; ++l) {
    k_agg<<<dim3((N + 3) / 4), dim3(256), 0, stream>>>(
        hb, row_start, packed, tblC, (u32*)zb, N);
    k_mlp<<<dim3(256), dim3(512), 0, stream>>>(
        zb, W1F, W2F, cB1, cB2, (u16*)act, stats + (size_t)l * 256, N, nTiles);
    if (l < L - 1) {
      k_bnapply<<<dim3(1024), dim3(256), 0, stream>>>(
          act, stats + (size_t)l * 256, cGamma + (size_t)l * 128, cBeta + (size_t)l * 128,
          invN, hb, N);
    }
  }
  k_final<<<dim3(1024), dim3(256), 0, stream>>>(
      act, stats + (size_t)(L - 1) * 256, cGamma + (size_t)(L - 1) * 128,
      cBeta + (size_t)(L - 1) * 128, invN, dflags, d_out, N);
}

// Round 10
// 454.476 us; speedup vs baseline: 1.6448x; 1.0369x over previous
//
#include <hip/hip_runtime.h>

typedef _Float16 f16;
typedef _Float16 f16x8 __attribute__((ext_vector_type(8)));
typedef _Float16 h2 __attribute__((ext_vector_type(2)));
typedef float f32x4 __attribute__((ext_vector_type(4)));
typedef unsigned short u16;
typedef unsigned int u32;

// ---------- conversions ----------
__device__ __forceinline__ float bf2f(u16 b) {
  union { u32 u; float f; } t; t.u = ((u32)b) << 16; return t.f;
}
__device__ __forceinline__ u16 f2bf(float f) {  // RNE float->bf16 bits
  union { float f; u32 u; } t; t.f = f;
  u32 u = t.u;
  return (u16)((u + 0x7FFFu + ((u >> 16) & 1u)) >> 16);
}
__device__ __forceinline__ u16 f2h_bits(float f) {
  f16 h = (f16)f;
  union { f16 h; u16 u; } t; t.h = h; return t.u;
}
__device__ __forceinline__ float2 up2(u32 p) {  // f16 pair -> float2
  union { u32 u; f16 h[2]; } t; t.u = p;
  float2 r; r.x = (float)t.h[0]; r.y = (float)t.h[1]; return r;
}
__device__ __forceinline__ u32 pk2(float x, float y) {  // float2 -> f16 pair
  return (u32)f2h_bits(x) | ((u32)f2h_bits(y) << 16);
}
__device__ __forceinline__ h2 asH2(u32 u) {
  union { u32 u; h2 h; } t; t.u = u; return t.h;
}
__device__ __forceinline__ h2 relu2(h2 a) {
#if __has_builtin(__builtin_elementwise_max)
  h2 z = {(_Float16)0, (_Float16)0};
  return __builtin_elementwise_max(a, z);
#else
  h2 r;
  r.x = a.x > (_Float16)0 ? a.x : (_Float16)0;
  r.y = a.y > (_Float16)0 ? a.y : (_Float16)0;
  return r;
#endif
}

// ---------------- dtype detection ----------------
__global__ void k_detect(const u16* __restrict__ elemRaw, const int* __restrict__ eiRaw,
                         int* __restrict__ dflags) {
  __shared__ int bad, nzOdd;
  if (threadIdx.x == 0) { bad = 0; nzOdd = 0; }
  __syncthreads();
  int myBad = 0;
  for (int i = threadIdx.x; i < 4096; i += 256) {
    float v = bf2f(elemRaw[i]);
    if (!(v > -0.2f && v < 0.2f)) myBad++;
  }
  if (myBad) atomicAdd(&bad, myBad);
  int myNz = 0;
  for (int i = threadIdx.x; i < 1024; i += 256)
    if (eiRaw[2 * i + 1] != 0) myNz++;  // int64 high words would be 0
  if (myNz) atomicAdd(&nzOdd, myNz);
  __syncthreads();
  if (threadIdx.x == 0) {
    dflags[0] = (bad == 0) ? 1 : 0;
    dflags[1] = (nzOdd > 16) ? 1 : 0;
  }
}

__global__ void k_canary(u32* __restrict__ out, const int* __restrict__ dflags,
                         int out_size, u32 pBf, u32 pF32) {
  int isbf = dflags[0];
  int words = isbf ? (out_size >> 1) : out_size;
  int i = blockIdx.x * 256 + threadIdx.x;
  if (i < words) out[i] = isbf ? pBf : pF32;
}

// ---------------- zero ----------------
__global__ void k_zero(int* counts, float* stats, int NPad) {
  int i = blockIdx.x * blockDim.x + threadIdx.x;
  if (i < NPad) counts[i] = 0;
  else if (i < NPad + 1280) stats[i - NPad] = 0.f;
}

// ---------------- combined canonicalize (+fused dst histogram) ----------------
__global__ void k_cvt(const int* __restrict__ xR, const int* __restrict__ eiR,
                      const int* __restrict__ eaR,
                      const u16* e0, const u16* e1, const u16* e2, const u16* e3,
                      const u16* e4, const u16* e5, const u16* e6, const u16* e7,
                      const u16* e8, const u16* e9,
                      const int* __restrict__ dflags,
                      int* __restrict__ x32, int* __restrict__ ei32, int* __restrict__ combo,
                      int* __restrict__ counts, float* __restrict__ dst,
                      int N, int E, int intBlocks) {
  if ((int)blockIdx.x < intBlocks) {
    int pi = blockIdx.x * 256 + threadIdx.x;
    int nPairs = N + 2 * E;
    if (pi >= nPairs) return;
    int is32 = dflags[1];
    const int* src; int local; int kind;
    if (pi < N) { src = xR; local = pi; kind = 0; }
    else if (pi < N + E) { src = eiR; local = pi - N; kind = 1; }
    else { src = eaR; local = pi - N - E; kind = 2; }
    int j0 = 2 * local;
    int v0, v1;
    if (is32) { int2 v = *(const int2*)(src + j0); v0 = v.x; v1 = v.y; }
    else      { int4 v = *(const int4*)(src + 2 * j0); v0 = v.x; v1 = v.z; }
    if (kind == 0) { x32[j0] = v0; x32[j0 + 1] = v1; }
    else if (kind == 1) {
      ei32[j0] = v0; ei32[j0 + 1] = v1;
      if (j0 >= E) {  // dst half
        atomicAdd(&counts[v0], 1);
        atomicAdd(&counts[v1], 1);
      }
    } else {
      combo[local] = v0 * 3 + v1;
    }
  } else {
    int i = (blockIdx.x - intBlocks) * 256 + threadIdx.x;
    if (i >= 83712) return;
    int isbf = dflags[0];
    const u16* src; int j;
    if      (i < 15104) { src = e0; j = i; }
    else if (i < 15616) { src = e1; j = i - 15104; }
    else if (i < 16128) { src = e2; j = i - 15616; }
    else if (i < 16512) { src = e3; j = i - 16128; }
    else if (i < 49280) { src = e4; j = i - 16512; }
    else if (i < 49536) { src = e5; j = i - 49280; }
    else if (i < 82304) { src = e6; j = i - 49536; }
    else if (i < 82432) { src = e7; j = i - 82304; }
    else if (i < 83072) { src = e8; j = i - 82432; }
    else                { src = e9; j = i - 83072; }
    dst[i] = isbf ? bf2f(src[j]) : ((const float*)src)[j];
  }
}

// ---------------- CSR scan ----------------
__global__ void k_chunksum(const int* __restrict__ counts, int* __restrict__ bsum) {
  int tid = threadIdx.x, lane = tid & 63, w = tid >> 6;
  const int4* c4 = (const int4*)(counts + blockIdx.x * 1024);
  int4 v = c4[tid];
  int s = v.x + v.y + v.z + v.w;
#pragma unroll
  for (int d = 1; d < 64; d <<= 1) s += __shfl_xor(s, d);
  __shared__ int ws[4];
  if (lane == 0) ws[w] = s;
  __syncthreads();
  if (tid == 0) bsum[blockIdx.x] = ws[0] + ws[1] + ws[2] + ws[3];
}

__global__ void k_chunkscan(const int* __restrict__ bsum, int* __restrict__ boff,
                            int* __restrict__ row_start, int N, int nCh) {
  int t = threadIdx.x;
  int v = (t < nCh) ? bsum[t] : 0;
  int incl = v;
#pragma unroll
  for (int d = 1; d < 64; d <<= 1) { int tmp = __shfl_up(incl, d); if (t >= d) incl += tmp; }
  boff[t] = incl - v;
  if (t == 63) row_start[N] = incl;  // = E
}

__global__ void k_scanapply(const int* __restrict__ counts, const int* __restrict__ boff,
                            int* __restrict__ row_start, int* __restrict__ cursor, int N) {
  int tid = threadIdx.x, lane = tid & 63, w = tid >> 6;
  int base = blockIdx.x * 1024 + tid * 4;
  int4 v = *(const int4*)(counts + base);
  int tsum = v.x + v.y + v.z + v.w;
  int incl = tsum;
#pragma unroll
  for (int d = 1; d < 64; d <<= 1) { int tmp = __shfl_up(incl, d); if (lane >= d) incl += tmp; }
  __shared__ int ws[4];
  if (lane == 63) ws[w] = incl;
  __syncthreads();
  int woff = 0;
  for (int j = 0; j < w; ++j) woff += ws[j];
  int excl = boff[blockIdx.x] + woff + incl - tsum;
  int e0 = excl, e1 = excl + v.x, e2 = e1 + v.y, e3 = e2 + v.z;
  if (base < N)     { row_start[base] = e0;     cursor[base] = e0; }
  if (base + 1 < N) { row_start[base + 1] = e1; cursor[base + 1] = e1; }
  if (base + 2 < N) { row_start[base + 2] = e2; cursor[base + 2] = e2; }
  if (base + 3 < N) { row_start[base + 3] = e3; cursor[base + 3] = e3; }
}

__global__ void k_scatter(const int* __restrict__ ei, const int* __restrict__ combo,
                          int* cursor, int* packed, int E) {
  int e = blockIdx.x * blockDim.x + threadIdx.x;
  if (e >= E) return;
  int s = ei[e], d = ei[E + e];
  int cb = combo[e];
  int pos = atomicAdd(&cursor[d], 1);
  packed[pos] = s | (cb << 20);  // src < 2^20, combo in [0,12)
}

// ---------------- fragment-ordered weights + bond table + h0 (merged) ----------------
__global__ void k_prep(const float* __restrict__ cflt, const int* __restrict__ x,
                       u32* __restrict__ W1F, u32* __restrict__ W2F,
                       u32* __restrict__ tblC, u32* __restrict__ hb, int N, int wtBlocks) {
  if ((int)blockIdx.x < wtBlocks) {
    const float* W1 = cflt + 16512;   // [128][256] row-major (k, n)
    const float* W2 = cflt + 49536;   // [256][128] row-major (k2, n2)
    const float* bt = cflt + 15616;
    const float* bd = cflt + 16128;
    int g = blockIdx.x * 256 + threadIdx.x;  // 0..16383 (one u32 of each table)
    {
      int e = g >> 2, wd = g & 3;
      int lane = e & 63, nt = (e >> 6) & 3, ks = (e >> 8) & 3, c = (e >> 10) & 3;
      int q = lane >> 4, lo = lane & 15;
      int n = c * 64 + nt * 16 + lo;
      int k0 = (ks * 4 + q) * 8 + wd * 2;
      W1F[g] = pk2(W1[k0 * 256 + n], W1[(k0 + 1) * 256 + n]);
    }
    {
      int e = g >> 2, wd = g & 3;
      int lane = e & 63, nt = (e >> 6) & 7, ks2 = (e >> 9) & 1, c = (e >> 10) & 3;
      int q = lane >> 4, lo = lane & 15;
      int n2 = nt * 16 + lo;
      int k20 = c * 64 + (ks2 * 4 + q) * 8 + wd * 2;
      W2F[g] = pk2(W2[k20 * 128 + n2], W2[(k20 + 1) * 128 + n2]);
    }
    if (g < 768) {
      int combo = g >> 6, l = g & 63, c0 = l * 2;
      int a0 = combo / 3, a1 = combo - a0 * 3;
      tblC[g] = pk2(bt[a0 * 128 + c0] + bd[a1 * 128 + c0],
                    bt[a0 * 128 + c0 + 1] + bd[a1 * 128 + c0 + 1]);
    }
  } else {
    const float* elem = cflt;
    const float* chir = cflt + 15104;
    int b = blockIdx.x - wtBlocks;
    int wv = (int)(threadIdx.x >> 6);
    int lane = threadIdx.x & 63;
    int node = b * 4 + wv;
    if (node >= N) return;
    int x0 = x[node * 2], x1 = x[node * 2 + 1];
    int c0 = lane * 2;
    float vx = elem[x0 * 128 + c0] + chir[x1 * 128 + c0];
    float vy = elem[x0 * 128 + c0 + 1] + chir[x1 * 128 + c0 + 1];
    hb[(size_t)node * 64 + lane] = pk2(vx, vy);
  }
}

// ---------------- gather/aggregate: 4 nodes per wave (16 lanes x 16B each) ----------------
// Lane l: sub = l>>4 (node within wave), li = l&15 (uint4 slot = dims li*8..li*8+8).
// 4 independent sub-uniform edge chains x unroll 4 -> 16 gathers (4 KB) in flight/wave.
__global__ __launch_bounds__(256) void k_agg(
    const u32* __restrict__ hb, const int* __restrict__ row_start,
    const int* __restrict__ packed, const u32* __restrict__ tblC,
    u32* __restrict__ z, int N) {
  __shared__ u32 tbl[768];  // [combo][64 u32] == [combo][16 uint4]
  for (int idx = threadIdx.x; idx < 768; idx += 256) tbl[idx] = tblC[idx];
  __syncthreads();
  const uint4* tbl4 = (const uint4*)tbl;
  const int tid = threadIdx.x;
  const int w = tid >> 6, lane = tid & 63;
  const int sub = lane >> 4, li = lane & 15;
  const int node = blockIdx.x * 16 + w * 4 + sub;
  if (node >= N) return;
  const uint4* hb4 = (const uint4*)hb;  // 16 uint4 per row
  uint4 sv = hb4[(size_t)node * 16 + li];
  float2 s0 = up2(sv.x), s1 = up2(sv.y), s2 = up2(sv.z), s3 = up2(sv.w);
  float ax0 = s0.x, ay0 = s0.y, ax1 = s1.x, ay1 = s1.y;
  float ax2 = s2.x, ay2 = s2.y, ax3 = s3.x, ay3 = s3.y;
  const int s_ = row_start[node], e_ = row_start[node + 1];
  int p = s_;
  for (; p + 4 <= e_; p += 4) {
    int k0 = packed[p], k1 = packed[p + 1], k2 = packed[p + 2], k3 = packed[p + 3];
    uint4 r0 = hb4[(size_t)(k0 & 0xFFFFF) * 16 + li];
    uint4 r1 = hb4[(size_t)(k1 & 0xFFFFF) * 16 + li];
    uint4 r2 = hb4[(size_t)(k2 & 0xFFFFF) * 16 + li];
    uint4 r3 = hb4[(size_t)(k3 & 0xFFFFF) * 16 + li];
    uint4 t0 = tbl4[(k0 >> 20) * 16 + li];
    uint4 t1 = tbl4[(k1 >> 20) * 16 + li];
    uint4 t2 = tbl4[(k2 >> 20) * 16 + li];
    uint4 t3 = tbl4[(k3 >> 20) * 16 + li];
    h2 m;
    m = relu2(asH2(r0.x) + asH2(t0.x)); ax0 += (float)m.x; ay0 += (float)m.y;
    m = relu2(asH2(r0.y) + asH2(t0.y)); ax1 += (float)m.x; ay1 += (float)m.y;
    m = relu2(asH2(r0.z) + asH2(t0.z)); ax2 += (float)m.x; ay2 += (float)m.y;
    m = relu2(asH2(r0.w) + asH2(t0.w)); ax3 += (float)m.x; ay3 += (float)m.y;
    m = relu2(asH2(r1.x) + asH2(t1.x)); ax0 += (float)m.x; ay0 += (float)m.y;
    m = relu2(asH2(r1.y) + asH2(t1.y)); ax1 += (float)m.x; ay1 += (float)m.y;
    m = relu2(asH2(r1.z) + asH2(t1.z)); ax2 += (float)m.x; ay2 += (float)m.y;
    m = relu2(asH2(r1.w) + asH2(t1.w)); ax3 += (float)m.x; ay3 += (float)m.y;
    m = relu2(asH2(r2.x) + asH2(t2.x)); ax0 += (float)m.x; ay0 += (float)m.y;
    m = relu2(asH2(r2.y) + asH2(t2.y)); ax1 += (float)m.x; ay1 += (float)m.y;
    m = relu2(asH2(r2.z) + asH2(t2.z)); ax2 += (float)m.x; ay2 += (float)m.y;
    m = relu2(asH2(r2.w) + asH2(t2.w)); ax3 += (float)m.x; ay3 += (float)m.y;
    m = relu2(asH2(r3.x) + asH2(t3.x)); ax0 += (float)m.x; ay0 += (float)m.y;
    m = relu2(asH2(r3.y) + asH2(t3.y)); ax1 += (float)m.x; ay1 += (float)m.y;
    m = relu2(asH2(r3.z) + asH2(t3.z)); ax2 += (float)m.x; ay2 += (float)m.y;
    m = relu2(asH2(r3.w) + asH2(t3.w)); ax3 += (float)m.x; ay3 += (float)m.y;
  }
  for (; p < e_; ++p) {
    int k0 = packed[p];
    uint4 r0 = hb4[(size_t)(k0 & 0xFFFFF) * 16 + li];
    uint4 t0 = tbl4[(k0 >> 20) * 16 + li];
    h2 m;
    m = relu2(asH2(r0.x) + asH2(t0.x)); ax0 += (float)m.x; ay0 += (float)m.y;
    m = relu2(asH2(r0.y) + asH2(t0.y)); ax1 += (float)m.x; ay1 += (float)m.y;
    m = relu2(asH2(r0.z) + asH2(t0.z)); ax2 += (float)m.x; ay2 += (float)m.y;
    m = relu2(asH2(r0.w) + asH2(t0.w)); ax3 += (float)m.x; ay3 += (float)m.y;
  }
  uint4 o;
  o.x = pk2(ax0, ay0); o.y = pk2(ax1, ay1); o.z = pk2(ax2, ay2); o.w = pk2(ax3, ay3);
  ((uint4*)z)[(size_t)node * 16 + li] = o;
}

// ---------------- persistent MLP: weights LDS-resident, one block per CU ----------------
__global__ __launch_bounds__(512, 2) void k_mlp(
    const u16* __restrict__ z, const u32* __restrict__ W1F, const u32* __restrict__ W2F,
    const float* __restrict__ b1, const float* __restrict__ b2,
    u16* __restrict__ act, float* __restrict__ statsL, int N, int nTiles) {
  __shared__ u32 sW1[16384];     // 64 KB fragment-ordered W1
  __shared__ u32 sW2[16384];     // 64 KB fragment-ordered W2
  __shared__ u16 sYp[8][1024];   // 16 KB: per-wave private Y (16x64, swizzled)
  __shared__ float sStats[256];  // 1 KB

  const int tid = threadIdx.x;
  const int w = tid >> 6, lane = tid & 63;
  const int lo = lane & 15, q = lane >> 4;

  if (tid < 256) sStats[tid] = 0.f;
  {
    const int4* gW1 = (const int4*)W1F;
    const int4* gW2 = (const int4*)W2F;
    int4* lW1 = (int4*)sW1;
    int4* lW2 = (int4*)sW2;
#pragma unroll
    for (int it = 0; it < 8; ++it) {
      int o = it * 512 + tid;
      lW1[o] = gW1[o];
      lW2[o] = gW2[o];
    }
  }
  __syncthreads();

  float rb1[16], rb2[8];
#pragma unroll
  for (int c = 0; c < 4; ++c)
#pragma unroll
    for (int nt = 0; nt < 4; ++nt)
      rb1[c * 4 + nt] = b1[c * 64 + nt * 16 + lo];
#pragma unroll
  for (int nt = 0; nt < 8; ++nt)
    rb2[nt] = b2[nt * 16 + lo];

  float aSum[8] = {}, aSq[8] = {};
  u16* myY = sYp[w];

  for (int t = blockIdx.x * 8 + w; t < nTiles; t += 2048) {
    const int row0 = t * 16;
    f16x8 a1[4];
    const char* zrow = (const char*)z + (size_t)(row0 + lo) * 256;
#pragma unroll
    for (int ks = 0; ks < 4; ++ks)
      a1[ks] = *(const f16x8*)(zrow + (ks * 4 + q) * 16);

    f32x4 accO[8] = {};
#pragma unroll
    for (int c = 0; c < 4; ++c) {
      f16x8 B1[16];
#pragma unroll
      for (int i = 0; i < 16; ++i)
        B1[i] = *(const f16x8*)((const char*)sW1 + ((c * 16 + i) << 10) + lane * 16);
      f32x4 acc1[4] = {};
#pragma unroll
      for (int ks = 0; ks < 4; ++ks)
#pragma unroll
        for (int nt = 0; nt < 4; ++nt)
          acc1[nt] = __builtin_amdgcn_mfma_f32_16x16x32_f16(a1[ks], B1[ks * 4 + nt], acc1[nt], 0, 0, 0);
#pragma unroll
      for (int nt = 0; nt < 4; ++nt) {
        int ycol = nt * 16 + lo;
        float bias = rb1[c * 4 + nt];
#pragma unroll
        for (int i = 0; i < 4; ++i) {
          int m = q * 4 + i;
          float v = fmaxf(acc1[nt][i] + bias, 0.f);
          myY[m * 64 + (((ycol >> 3) ^ (m & 7)) << 3) + (ycol & 7)] = f2h_bits(v);
        }
      }
      f16x8 B2[16];
#pragma unroll
      for (int i = 0; i < 16; ++i)
        B2[i] = *(const f16x8*)((const char*)sW2 + ((c * 16 + i) << 10) + lane * 16);
#pragma unroll
      for (int ks2 = 0; ks2 < 2; ++ks2) {
        int kq2 = ks2 * 4 + q;
        f16x8 a2 = *(const f16x8*)(myY + lo * 64 + ((kq2 ^ (lo & 7)) << 3));
#pragma unroll
        for (int nt = 0; nt < 8; ++nt)
          accO[nt] = __builtin_amdgcn_mfma_f32_16x16x32_f16(a2, B2[ks2 * 8 + nt], accO[nt], 0, 0, 0);
      }
    }
#pragma unroll
    for (int nt = 0; nt < 8; ++nt) {
      int n2 = nt * 16 + lo;
      float bias = rb2[nt];
#pragma unroll
      for (int i = 0; i < 4; ++i) {
        int row = row0 + q * 4 + i;
        float v = accO[nt][i] + bias;
        act[(size_t)row * 128 + n2] = f2h_bits(v);
        if (row < N) { aSum[nt] += v; aSq[nt] += v * v; }
      }
    }
  }

#pragma unroll
  for (int nt = 0; nt < 8; ++nt) {
    float s = aSum[nt], s2 = aSq[nt];
    s += __shfl_xor(s, 16); s += __shfl_xor(s, 32);
    s2 += __shfl_xor(s2, 16); s2 += __shfl_xor(s2, 32);
    if (q == 0) {
      atomicAdd(&sStats[nt * 16 + lo], s);
      atomicAdd(&sStats[128 + nt * 16 + lo], s2);
    }
  }
  __syncthreads();
  if (tid < 256) atomicAdd(&statsL[tid], sStats[tid]);
}

// ---------------- BN apply + relu (per node, computes sc/sh in-block) ----------------
__global__ __launch_bounds__(256) void k_bnapply(
    const u32* __restrict__ act, const float* __restrict__ statsL,
    const float* __restrict__ gamma, const float* __restrict__ beta,
    float invN, u32* __restrict__ hb, int N) {
  __shared__ float ssc[128], ssh[128];
  int tid = threadIdx.x;
  if (tid < 128) {
    float mean = statsL[tid] * invN;
    float var = statsL[128 + tid] * invN - mean * mean;
    float inv = rsqrtf(var + 1e-5f);
    float scv = gamma[tid] * inv;
    ssc[tid] = scv;
    ssh[tid] = beta[tid] - mean * scv;
  }
  __syncthreads();
  int total = N * 64;
  for (int i = blockIdx.x * 256 + tid; i < total; i += gridDim.x * 256) {
    int c0 = (i & 63) * 2;
    float2 v = up2(act[i]);
    float ox = fmaxf(v.x * ssc[c0] + ssh[c0], 0.f);
    float oy = fmaxf(v.y * ssc[c0 + 1] + ssh[c0 + 1], 0.f);
    hb[i] = pk2(ox, oy);
  }
}

// ---------------- final: BN (no relu) -> output dtype ----------------
__global__ __launch_bounds__(256) void k_final(
    const u32* __restrict__ act, const float* __restrict__ statsL,
    const float* __restrict__ gamma, const float* __restrict__ beta,
    float invN, const int* __restrict__ dflags, void* __restrict__ outv, int N) {
  __shared__ float ssc[128], ssh[128];
  int tid = threadIdx.x;
  if (tid < 128) {
    float mean = statsL[tid] * invN;
    float var = statsL[128 + tid] * invN - mean * mean;
    float inv = rsqrtf(var + 1e-5f);
    float scv = gamma[tid] * inv;
    ssc[tid] = scv;
    ssh[tid] = beta[tid] - mean * scv;
  }
  __syncthreads();
  int isbf = dflags[0];
  int total = N * 64;
  for (int i = blockIdx.x * 256 + tid; i < total; i += gridDim.x * 256) {
    int c0 = (i & 63) * 2;
    float2 v = up2(act[i]);
    float ox = v.x * ssc[c0] + ssh[c0];
    float oy = v.y * ssc[c0 + 1] + ssh[c0 + 1];
    if (isbf) ((u32*)outv)[i] = (u32)f2bf(ox) | ((u32)f2bf(oy) << 16);
    else { float2 o; o.x = ox; o.y = oy; ((float2*)outv)[i] = o; }
  }
}

extern "C" void kernel_launch(void* const* d_in, const int* in_sizes, int n_in,
                              void* d_out, int out_size, void* d_ws, size_t ws_size,
                              hipStream_t stream) {
  const int* xR  = (const int*)d_in[0];
  const int* eiR = (const int*)d_in[1];
  const int* eaR = (const int*)d_in[2];
  const u16* emR = (const u16*)d_in[3];
  const u16* chR = (const u16*)d_in[4];
  const u16* btR = (const u16*)d_in[5];
  const u16* bdR = (const u16*)d_in[6];
  const u16* W1R = (const u16*)d_in[7];
  const u16* b1R = (const u16*)d_in[8];
  const u16* W2R = (const u16*)d_in[9];
  const u16* b2R = (const u16*)d_in[10];
  const u16* gR  = (const u16*)d_in[11];
  const u16* beR = (const u16*)d_in[12];

  const int N = in_sizes[0] / 2;      // 50000
  const int E = in_sizes[1] / 2;      // 600000
  const int L = in_sizes[11] / 128;   // 5
  const int Mpad = ((N + 63) / 64) * 64;
  const int nCh = (N + 1023) / 1024;
  const int NPad = nCh * 1024;
  const int nTiles = (N + 15) / 16;   // 3125

  char* base = (char*)d_ws;
  size_t off = 0;
  auto take = [&](size_t bytes) -> void* {
    void* p = base + off;
    off += (bytes + 255) & ~(size_t)255;
    return p;
  };
  int*   dflags    = (int*)  take(256);
  int*   x32       = (int*)  take((size_t)2 * N * 4);
  int*   ei32      = (int*)  take((size_t)2 * E * 4);
  int*   combo     = (int*)  take((size_t)E * 4);
  float* cflt      = (float*)take(83712 * 4);
  u32*   act       = (u32*)  take((size_t)Mpad * 64 * 4);   // raw MLP out (f16 pairs)
  u32*   hb        = (u32*)  take((size_t)Mpad * 64 * 4);   // BN-applied relu'd h
  u16*   zb        = (u16*)  take((size_t)Mpad * 128 * 2);
  int*   packed    = (int*)  take((size_t)E * 4);
  int*   row_start = (int*)  take((size_t)(N + 1) * 4);
  int*   cursor    = (int*)  take((size_t)N * 4);
  int*   counts    = (int*)  take((size_t)NPad * 4);
  int*   bsum      = (int*)  take(64 * 4);
  int*   boff      = (int*)  take(64 * 4);
  float* stats     = (float*)take((size_t)L * 256 * 4);
  u32*   W1F       = (u32*)  take(16384 * 4);
  u32*   W2F       = (u32*)  take(16384 * 4);
  u32*   tblC      = (u32*)  take(768 * 4);
  const size_t need = off;
  (void)n_in;

  float* cB1 = cflt + 49280;
  float* cB2 = cflt + 82304;
  float* cGamma = cflt + 82432;
  float* cBeta = cflt + 83072;

  k_detect<<<dim3(1), dim3(256), 0, stream>>>(emR, eiR, dflags);

  if (need > ws_size) {
    k_canary<<<dim3((out_size + 255) / 256), dim3(256), 0, stream>>>(
        (u32*)d_out, dflags, out_size, 0x40004000u, 0x40000000u);
    return;
  }

  k_zero<<<dim3((NPad + 1280 + 255) / 256), dim3(256), 0, stream>>>(counts, stats, NPad);

  const int nPairs = N + 2 * E;
  const int intBlocks = (nPairs + 255) / 256;
  const int fltBlocks = (83712 + 255) / 256;
  k_cvt<<<dim3(intBlocks + fltBlocks), dim3(256), 0, stream>>>(
      xR, eiR, eaR, emR, chR, btR, bdR, W1R, b1R, W2R, b2R, gR, beR,
      dflags, x32, ei32, combo, counts, cflt, N, E, intBlocks);

  k_chunksum<<<dim3(nCh), dim3(256), 0, stream>>>(counts, bsum);
  k_chunkscan<<<dim3(1), dim3(64), 0, stream>>>(bsum, boff, row_start, N, nCh);
  k_scanapply<<<dim3(nCh), dim3(256), 0, stream>>>(counts, boff, row_start, cursor, N);
  k_scatter<<<dim3((E + 255) / 256), dim3(256), 0, stream>>>(ei32, combo, cursor, packed, E);

  const int wtBlocks = 64;  // 16384 threads for W1F/W2F words
  k_prep<<<dim3(wtBlocks + (N + 3) / 4), dim3(256), 0, stream>>>(
      cflt, x32, W1F, W2F, tblC, hb, N, wtBlocks);

  const float invN = 1.0f / (float)N;
  for (int l = 0; l < L; ++l) {
    k_agg<<<dim3((N + 15) / 16), dim3(256), 0, stream>>>(
        hb, row_start, packed, tblC, (u32*)zb, N);
    k_mlp<<<dim3(256), dim3(512), 0, stream>>>(
        zb, W1F, W2F, cB1, cB2, (u16*)act, stats + (size_t)l * 256, N, nTiles);
    if (l < L - 1) {
      k_bnapply<<<dim3(1024), dim3(256), 0, stream>>>(
          act, stats + (size_t)l * 256, cGamma + (size_t)l * 128, cBeta + (size_t)l * 128,
          invN, hb, N);
    }
  }
  k_final<<<dim3(1024), dim3(256), 0, stream>>>(
      act, stats + (size_t)(L - 1) * 256, cGamma + (size_t)(L - 1) * 128,
      cBeta + (size_t)(L - 1) * 128, invN, dflags, d_out, N);
}